// Round 1
// baseline (28488.983 us; speedup 1.0000x reference)
//
#include <hip/hip_runtime.h>

#define B_ 16
#define L_ 96
#define N_ 1024
#define EMB_ 64

// ---------------- generic fp32 GEMM (NN): C = A@B (+bias per col) ----------------
// A: M x K (stride lda), B: K x N (stride ldb), C: M x N (stride ldc)
__global__ __launch_bounds__(256) void gemm_nn(
    const float* __restrict__ A, const float* __restrict__ Bm, float* __restrict__ C,
    int M, int N, int K, int lda, int ldb, int ldc, const float* __restrict__ bias)
{
    __shared__ float As[64][17];
    __shared__ __align__(16) float Bs[16][64];
    const int tid = threadIdx.x;
    const int tx = tid & 15, ty = tid >> 4;
    const int row0 = blockIdx.y * 64, col0 = blockIdx.x * 64;
    float acc[4][4] = {};
    const int ak = tid & 15, ar = tid >> 4;
    const int bc = tid & 63, bk = tid >> 6;
    for (int k0 = 0; k0 < K; k0 += 16) {
#pragma unroll
        for (int i = 0; i < 4; ++i) {
            int r = ar + i * 16;
            int gr = row0 + r, gk = k0 + ak;
            As[r][ak] = (gr < M && gk < K) ? A[(size_t)gr * lda + gk] : 0.f;
        }
#pragma unroll
        for (int i = 0; i < 4; ++i) {
            int kk = bk + i * 4;
            int gk = k0 + kk, gc = col0 + bc;
            Bs[kk][bc] = (gk < K && gc < N) ? Bm[(size_t)gk * ldb + gc] : 0.f;
        }
        __syncthreads();
#pragma unroll
        for (int kk = 0; kk < 16; ++kk) {
            float4 b4 = *reinterpret_cast<const float4*>(&Bs[kk][tx * 4]);
            float a0 = As[ty * 4 + 0][kk];
            float a1 = As[ty * 4 + 1][kk];
            float a2 = As[ty * 4 + 2][kk];
            float a3 = As[ty * 4 + 3][kk];
            acc[0][0] += a0 * b4.x; acc[0][1] += a0 * b4.y; acc[0][2] += a0 * b4.z; acc[0][3] += a0 * b4.w;
            acc[1][0] += a1 * b4.x; acc[1][1] += a1 * b4.y; acc[1][2] += a1 * b4.z; acc[1][3] += a1 * b4.w;
            acc[2][0] += a2 * b4.x; acc[2][1] += a2 * b4.y; acc[2][2] += a2 * b4.z; acc[2][3] += a2 * b4.w;
            acc[3][0] += a3 * b4.x; acc[3][1] += a3 * b4.y; acc[3][2] += a3 * b4.z; acc[3][3] += a3 * b4.w;
        }
        __syncthreads();
    }
#pragma unroll
    for (int i = 0; i < 4; ++i) {
        int gr = row0 + ty * 4 + i;
        if (gr >= M) continue;
#pragma unroll
        for (int j = 0; j < 4; ++j) {
            int gc = col0 + tx * 4 + j;
            if (gc >= N) continue;
            float v = acc[i][j];
            if (bias) v += bias[gc];
            C[(size_t)gr * ldc + gc] = v;
        }
    }
}

// ---------------- fp32 GEMM (NT): C = alpha * A@B^T ; M=N=1024, K<=64 ----------------
__global__ __launch_bounds__(256) void gemm_nt(
    const float* __restrict__ A, const float* __restrict__ Bm, float* __restrict__ C,
    int N, int K, float alpha)
{
    __shared__ float As[64][65];
    __shared__ float Bs[64][65];
    const int tid = threadIdx.x;
    const int row0 = blockIdx.y * 64, col0 = blockIdx.x * 64;
    for (int idx = tid; idx < 64 * K; idx += 256) {
        int r = idx / K, c = idx % K;
        As[r][c] = A[(size_t)(row0 + r) * K + c];
        Bs[r][c] = Bm[(size_t)(col0 + r) * K + c];
    }
    __syncthreads();
    const int tx = tid & 15, ty = tid >> 4;
    float acc[4][4] = {};
    for (int c = 0; c < K; ++c) {
        float a[4], b[4];
#pragma unroll
        for (int i = 0; i < 4; ++i) a[i] = As[ty * 4 + i][c];
#pragma unroll
        for (int j = 0; j < 4; ++j) b[j] = Bs[tx * 4 + j][c];
#pragma unroll
        for (int i = 0; i < 4; ++i)
#pragma unroll
            for (int j = 0; j < 4; ++j) acc[i][j] += a[i] * b[j];
    }
#pragma unroll
    for (int i = 0; i < 4; ++i)
#pragma unroll
        for (int j = 0; j < 4; ++j)
            C[(size_t)(row0 + ty * 4 + i) * N + col0 + tx * 4 + j] = alpha * acc[i][j];
}

// ---------------- row softmax over 1024 cols, optional relu-before ----------------
__global__ __launch_bounds__(256) void row_softmax(
    const float* __restrict__ in, float* __restrict__ out, int ostride, int relu)
{
    const float* rp = in + (size_t)blockIdx.x * N_;
    float* op = out + (size_t)blockIdx.x * ostride;
    const int tid = threadIdx.x;
    float v[4];
#pragma unroll
    for (int j = 0; j < 4; ++j) {
        float x = rp[tid + 256 * j];
        if (relu) x = fmaxf(x, 0.f);
        v[j] = x;
    }
    float m = fmaxf(fmaxf(v[0], v[1]), fmaxf(v[2], v[3]));
#pragma unroll
    for (int off = 32; off > 0; off >>= 1) m = fmaxf(m, __shfl_xor(m, off));
    __shared__ float red[4], red2[4];
    int w = tid >> 6;
    if ((tid & 63) == 0) red[w] = m;
    __syncthreads();
    m = fmaxf(fmaxf(red[0], red[1]), fmaxf(red[2], red[3]));
    float s = 0.f;
#pragma unroll
    for (int j = 0; j < 4; ++j) { v[j] = expf(v[j] - m); s += v[j]; }
#pragma unroll
    for (int off = 32; off > 0; off >>= 1) s += __shfl_xor(s, off);
    if ((tid & 63) == 0) red2[w] = s;
    __syncthreads();
    s = red2[0] + red2[1] + red2[2] + red2[3];
    float inv = 1.f / s;
#pragma unroll
    for (int j = 0; j < 4; ++j) op[tid + 256 * j] = v[j] * inv;
}

// ---------------- Wgcat[e][g*64+f] = Wg[g][e][f] ----------------
__global__ __launch_bounds__(256) void wgcat_kernel(const float* __restrict__ Wg,
                                                    float* __restrict__ Wgcat)
{
    int i = blockIdx.x * 256 + threadIdx.x;  // 4*64*64 = 16384
    int g = i >> 12, e = (i >> 6) & 63, f = i & 63;
    Wgcat[e * 256 + g * 64 + f] = Wg[i];
}

// ---------------- folded gate bias: bgconst[g*64+f] = bg[g][f] + sum_e bconst[e]*Wg[g][e][f]
//                  bconst[e] = bm[e] + sum_kp sum_f bv[f]*Wm[kp][f][e]  ----------------
__global__ __launch_bounds__(256) void bias_kernel(
    const float* __restrict__ bvz, const float* __restrict__ Wmz, const float* __restrict__ bmz,
    const float* __restrict__ Wgz, const float* __restrict__ bgz, float* __restrict__ bgconst)
{
    __shared__ float bconst[64];
    const int tid = threadIdx.x;
    if (tid < 64) {
        float s = bmz[tid];
        for (int kp = 0; kp < 3; ++kp)
            for (int f = 0; f < 64; ++f) s += bvz[f] * Wmz[kp * 4096 + f * 64 + tid];
        bconst[tid] = s;
    }
    __syncthreads();
    int g = tid >> 6, fo = tid & 63;
    float s = bgz[g * 64 + fo];
    for (int e = 0; e < 64; ++e) s += bconst[e] * Wgz[g * 4096 + e * 64 + fo];
    bgconst[tid] = s;
}

// ---------------- layer-0 Vcat build straight from history (C=3) ----------------
// Vcat[(kp*N+n)][ (l*B+b)*64+e ] = sum_c hist[b][l0+l][n][c] * W[kp][c][e]
__global__ __launch_bounds__(256) void vcat0_kernel(
    const float* __restrict__ hist, const float* __restrict__ W,
    float* __restrict__ Vcat, int l0, int LC)
{
    __shared__ float Ws[576];
    const int tid = threadIdx.x;
    for (int i = tid; i < 576; i += 256) Ws[i] = W[i];
    __syncthreads();
    const int e = tid & 63;
    const int rr = blockIdx.x * 4 + (tid >> 6);   // (n*LC + l)*16 + b
    const int b = rr & 15;
    const int t2 = rr >> 4;
    const int l = t2 % LC;
    const int n = t2 / LC;
    const float* xp = hist + (((size_t)b * L_ + (l0 + l)) * N_ + n) * 3;
    const float x0 = xp[0], x1 = xp[1], x2 = xp[2];
    const size_t LCB64 = (size_t)LC * B_ * 64;
    const size_t colb = ((size_t)l * B_ + b) * 64 + e;
#pragma unroll
    for (int kp = 0; kp < 3; ++kp) {
        float r = x0 * Ws[kp * 192 + e] + x1 * Ws[kp * 192 + 64 + e] + x2 * Ws[kp * 192 + 128 + e];
        Vcat[(size_t)(kp * N_ + n) * LCB64 + colb] = r;
    }
}

// ---------------- LSTM pointwise scan over a chunk ----------------
// gates rows (n*LC+l)*16+b, cols g*64+e.  ct layout (n*16+b)*64+e.
__global__ __launch_bounds__(256) void scan_kernel(
    const float* __restrict__ gates, float* __restrict__ ct_buf,
    float* __restrict__ ht_out, float* __restrict__ htlast,
    int LC, int l0, int initct)
{
    const int tid = threadIdx.x;
    const int e = tid & 63;
    const int p = blockIdx.x * 4 + (tid >> 6);   // n*16+b
    const int n = p >> 4, b = p & 15;
    const size_t ci = (size_t)p * 64 + e;
    float ct = initct ? 0.f : ct_buf[ci];
    for (int l = 0; l < LC; ++l) {
        const size_t row = ((size_t)n * LC + l) * B_ + b;
        const float* g = gates + row * 256;
        float gf = g[e], gi = g[64 + e], gg = g[128 + e], go = g[192 + e];
        float f  = 1.f / (1.f + expf(-gf));
        float i_ = 1.f / (1.f + expf(-gi));
        float g_ = tanhf(gg);
        float o  = 1.f / (1.f + expf(-go));
        ct = f * ct + i_ * g_;
        float ht = o * tanhf(ct);
        if (ht_out) ht_out[row * 64 + e] = ht;
        if (htlast && (l0 + l == L_ - 1)) htlast[ci] = ht;
    }
    ct_buf[ci] = ct;
}

// ---------------- decoder: out[b][o][n] ----------------
__global__ __launch_bounds__(256) void decoder_kernel(
    const float* __restrict__ h0, const float* __restrict__ h1,
    const float* __restrict__ Wdec, const float* __restrict__ bdec,
    const float* __restrict__ Wout, const float* __restrict__ bout,
    float* __restrict__ outp)
{
    __shared__ float Wd[12 * 2 * 64];
    __shared__ float Wo[144];
    __shared__ float bd[12], bo[12];
    const int tid = threadIdx.x;
    for (int i = tid; i < 12 * 2 * 64; i += 256) Wd[i] = Wdec[i];
    for (int i = tid; i < 144; i += 256) Wo[i] = Wout[i];
    if (tid < 12) { bd[tid] = bdec[tid]; bo[tid] = bout[tid]; }
    __syncthreads();
    const int gid = blockIdx.x * 256 + tid;   // b*1024 + n
    const int b = gid >> 10, n = gid & 1023;
    const float* h0r = h0 + ((size_t)n * 16 + b) * 64;
    const float* h1r = h1 + ((size_t)n * 16 + b) * 64;
    float dec[12];
#pragma unroll
    for (int o = 0; o < 12; ++o) dec[o] = bd[o];
    for (int e = 0; e < 64; ++e) {
        float v0 = h0r[e], v1 = h1r[e];
#pragma unroll
        for (int o = 0; o < 12; ++o) dec[o] += v0 * Wd[o * 128 + e] + v1 * Wd[o * 128 + 64 + e];
    }
#pragma unroll
    for (int o = 0; o < 12; ++o) {
        float s = bo[o];
#pragma unroll
        for (int p = 0; p < 12; ++p) s += Wo[o * 12 + p] * dec[p];
        outp[((size_t)b * 12 + o) * 1024 + n] = s;
    }
}

extern "C" void kernel_launch(void* const* d_in, const int* in_sizes, int n_in,
                              void* d_out, int out_size, void* d_ws, size_t ws_size,
                              hipStream_t stream)
{
    const float* hist = (const float*)d_in[0];
    const float* adj  = (const float*)d_in[1];
    const float* Wv0  = (const float*)d_in[2];
    const float* Wv1  = (const float*)d_in[3];
    const float* bv   = (const float*)d_in[4];
    const float* E    = (const float*)d_in[5];
    const float* Wq   = (const float*)d_in[6];
    const float* Wk   = (const float*)d_in[7];
    const float* Eg1  = (const float*)d_in[8];
    const float* Eg2  = (const float*)d_in[9];
    const float* Wmix = (const float*)d_in[10];
    const float* bmix = (const float*)d_in[11];
    const float* Wg   = (const float*)d_in[12];
    const float* bg   = (const float*)d_in[13];
    const float* Wdec = (const float*)d_in[14];
    const float* bdec = (const float*)d_in[15];
    const float* Wout = (const float*)d_in[16];
    const float* bout = (const float*)d_in[17];
    float* outp = (float*)d_out;
    (void)in_sizes; (void)n_in; (void)out_size;

    char* ws = (char*)d_ws;
    size_t off = 0;
    auto alloc = [&](size_t bytes) -> float* {
        float* p = (float*)(ws + off);
        off += (bytes + 255) & ~(size_t)255;
        return p;
    };
    float* Mcat0 = alloc((size_t)1024 * 3072 * 4);   // (N x 3N): cols [M1 | M2 | attn]
    float* Mcat1 = alloc((size_t)1024 * 3072 * 4);
    float* qb    = alloc((size_t)1024 * 64 * 4);
    float* kb    = alloc((size_t)1024 * 64 * 4);
    float* logits= alloc((size_t)1024 * 1024 * 4);
    float* adp   = alloc((size_t)1024 * 1024 * 4);
    float* Wvc0  = alloc(3 * 3 * 64 * 4);
    float* Wvc1  = alloc(3 * 64 * 64 * 4);
    float* Wgc0  = alloc(64 * 256 * 4);
    float* Wgc1  = alloc(64 * 256 * 4);
    float* bgc0  = alloc(256 * 4);
    float* bgc1  = alloc(256 * 4);
    float* ct0   = alloc((size_t)N_ * B_ * 64 * 4);
    float* ct1   = alloc((size_t)N_ * B_ * 64 * 4);
    float* hl0   = alloc((size_t)N_ * B_ * 64 * 4);
    float* hl1   = alloc((size_t)N_ * B_ * 64 * 4);
    size_t fixed = off;

    // chunk length over L: buffers cost ~37.75 MB per unit LC
    static const int divs[] = {16, 12, 8, 6, 4, 3, 2, 1};
    int LC = 1;
    for (int di = 0; di < 8; ++di) {
        if (fixed + (size_t)divs[di] * 37748736ull + 8192 <= ws_size) { LC = divs[di]; break; }
    }
    float* Vcat  = alloc((size_t)LC * 12582912ull);   // 3N x (LC*B*64)
    float* HG    = alloc((size_t)LC * 4194304ull);    // N  x (LC*B*64)
    float* gates = alloc((size_t)LC * 16777216ull);   // (N*LC*B) x 256
    float* ht0c  = alloc((size_t)LC * 4194304ull);    // (N*LC*B) x 64

    dim3 blk(256);
    const float* Wvz[2] = {Wv0, Wv1};
    const int invz[2] = {3, 64};
    float* McatA[2] = {Mcat0, Mcat1};
    float* Wvc[2] = {Wvc0, Wvc1};
    float* Wgc[2] = {Wgc0, Wgc1};
    float* bgc[2] = {bgc0, bgc1};

    for (int z = 0; z < 2; ++z) {
        const float* Ez = E + (size_t)z * N_ * 64;
        gemm_nn<<<dim3(1, 16), blk, 0, stream>>>(Ez, Wq + z * 4096, qb, 1024, 64, 64, 64, 64, 64, nullptr);
        gemm_nn<<<dim3(1, 16), blk, 0, stream>>>(Ez, Wk + z * 4096, kb, 1024, 64, 64, 64, 64, 64, nullptr);
        gemm_nt<<<dim3(16, 16), blk, 0, stream>>>(qb, kb, logits, 1024, 64, 0.125f);
        float* attnp = McatA[z] + 2048;  // cols 2048..3071 of Mcat (stride 3072)
        row_softmax<<<1024, blk, 0, stream>>>(logits, attnp, 3072, 0);
        gemm_nt<<<dim3(16, 16), blk, 0, stream>>>(Eg1 + z * 16384, Eg2 + z * 16384, logits, 1024, 16, 1.f);
        row_softmax<<<1024, blk, 0, stream>>>(logits, adp, 1024, 1);
        // M1 = adj@attn -> cols 0..1023 ; M2 = adp@attn -> cols 1024..2047
        gemm_nn<<<dim3(16, 16), blk, 0, stream>>>(adj, attnp, McatA[z], 1024, 1024, 1024, 1024, 3072, 3072, nullptr);
        gemm_nn<<<dim3(16, 16), blk, 0, stream>>>(adp, attnp, McatA[z] + 1024, 1024, 1024, 1024, 1024, 3072, 3072, nullptr);
        for (int kp = 0; kp < 3; ++kp)
            gemm_nn<<<dim3(1, 1), blk, 0, stream>>>(Wvz[z], Wmix + z * 12288 + kp * 4096,
                Wvc[z] + kp * invz[z] * 64, invz[z], 64, 64, 64, 64, 64, nullptr);
        wgcat_kernel<<<64, blk, 0, stream>>>(Wg + z * 16384, Wgc[z]);
        bias_kernel<<<1, blk, 0, stream>>>(bv + z * 64, Wmix + z * 12288, bmix + z * 64,
            Wg + z * 16384, bg + z * 256, bgc[z]);
    }

    const int nch = L_ / LC;
    const int Mrows = N_ * LC * B_;
    for (int c = 0; c < nch; ++c) {
        const int l0 = c * LC;
        // ---- layer 0 ----
        vcat0_kernel<<<LC * 4096, blk, 0, stream>>>(hist, Wvc0, Vcat, l0, LC);
        gemm_nn<<<dim3(LC * 16, 16), blk, 0, stream>>>(Mcat0, Vcat, HG,
            1024, LC * 1024, 3072, 3072, LC * 1024, LC * 1024, nullptr);
        gemm_nn<<<dim3(4, Mrows / 64), blk, 0, stream>>>(HG, Wgc0, gates,
            Mrows, 256, 64, 64, 256, 256, bgc0);
        scan_kernel<<<4096, blk, 0, stream>>>(gates, ct0, ht0c, hl0, LC, l0, c == 0);
        // ---- layer 1 ----
        for (int kp = 0; kp < 3; ++kp)
            gemm_nn<<<dim3(1, Mrows / 64), blk, 0, stream>>>(ht0c, Wvc1 + kp * 4096,
                Vcat + (size_t)kp * Mrows * 64, Mrows, 64, 64, 64, 64, 64, nullptr);
        gemm_nn<<<dim3(LC * 16, 16), blk, 0, stream>>>(Mcat1, Vcat, HG,
            1024, LC * 1024, 3072, 3072, LC * 1024, LC * 1024, nullptr);
        gemm_nn<<<dim3(4, Mrows / 64), blk, 0, stream>>>(HG, Wgc1, gates,
            Mrows, 256, 64, 64, 256, 256, bgc1);
        scan_kernel<<<4096, blk, 0, stream>>>(gates, ct1, nullptr, hl1, LC, l0, c == 0);
    }
    decoder_kernel<<<64, blk, 0, stream>>>(hl0, hl1, Wdec, bdec, Wout, bout, outp);
}

// Round 2
// 5352.217 us; speedup vs baseline: 5.3228x; 5.3228x over previous
//
#include <hip/hip_runtime.h>
#include <hip/hip_bf16.h>

#define B_ 16
#define L_ 96
#define N_ 1024
#define EMB_ 64

typedef __hip_bfloat16 bf16;
typedef __attribute__((ext_vector_type(4))) float f32x4;
typedef __attribute__((ext_vector_type(8))) short s16x8;

// ================= fp32 GEMM (NN) for setup =================
__global__ __launch_bounds__(256) void gemm_nn(
    const float* __restrict__ A, const float* __restrict__ Bm, float* __restrict__ C,
    int M, int N, int K, int lda, int ldb, int ldc, const float* __restrict__ bias)
{
    __shared__ float As[64][17];
    __shared__ __align__(16) float Bs[16][64];
    const int tid = threadIdx.x;
    const int tx = tid & 15, ty = tid >> 4;
    const int row0 = blockIdx.y * 64, col0 = blockIdx.x * 64;
    float acc[4][4] = {};
    const int ak = tid & 15, ar = tid >> 4;
    const int bc = tid & 63, bk = tid >> 6;
    for (int k0 = 0; k0 < K; k0 += 16) {
#pragma unroll
        for (int i = 0; i < 4; ++i) {
            int r = ar + i * 16;
            int gr = row0 + r, gk = k0 + ak;
            As[r][ak] = (gr < M && gk < K) ? A[(size_t)gr * lda + gk] : 0.f;
        }
#pragma unroll
        for (int i = 0; i < 4; ++i) {
            int kk = bk + i * 4;
            int gk = k0 + kk, gc = col0 + bc;
            Bs[kk][bc] = (gk < K && gc < N) ? Bm[(size_t)gk * ldb + gc] : 0.f;
        }
        __syncthreads();
#pragma unroll
        for (int kk = 0; kk < 16; ++kk) {
            float4 b4 = *reinterpret_cast<const float4*>(&Bs[kk][tx * 4]);
            float a0 = As[ty * 4 + 0][kk];
            float a1 = As[ty * 4 + 1][kk];
            float a2 = As[ty * 4 + 2][kk];
            float a3 = As[ty * 4 + 3][kk];
            acc[0][0] += a0 * b4.x; acc[0][1] += a0 * b4.y; acc[0][2] += a0 * b4.z; acc[0][3] += a0 * b4.w;
            acc[1][0] += a1 * b4.x; acc[1][1] += a1 * b4.y; acc[1][2] += a1 * b4.z; acc[1][3] += a1 * b4.w;
            acc[2][0] += a2 * b4.x; acc[2][1] += a2 * b4.y; acc[2][2] += a2 * b4.z; acc[2][3] += a2 * b4.w;
            acc[3][0] += a3 * b4.x; acc[3][1] += a3 * b4.y; acc[3][2] += a3 * b4.z; acc[3][3] += a3 * b4.w;
        }
        __syncthreads();
    }
#pragma unroll
    for (int i = 0; i < 4; ++i) {
        int gr = row0 + ty * 4 + i;
        if (gr >= M) continue;
#pragma unroll
        for (int j = 0; j < 4; ++j) {
            int gc = col0 + tx * 4 + j;
            if (gc >= N) continue;
            float v = acc[i][j];
            if (bias) v += bias[gc];
            C[(size_t)gr * ldc + gc] = v;
        }
    }
}

// ================= fp32 GEMM (NT) small, for setup =================
__global__ __launch_bounds__(256) void gemm_nt(
    const float* __restrict__ A, const float* __restrict__ Bm, float* __restrict__ C,
    int N, int K, float alpha)
{
    __shared__ float As[64][65];
    __shared__ float Bs[64][65];
    const int tid = threadIdx.x;
    const int row0 = blockIdx.y * 64, col0 = blockIdx.x * 64;
    for (int idx = tid; idx < 64 * K; idx += 256) {
        int r = idx / K, c = idx % K;
        As[r][c] = A[(size_t)(row0 + r) * K + c];
        Bs[r][c] = Bm[(size_t)(col0 + r) * K + c];
    }
    __syncthreads();
    const int tx = tid & 15, ty = tid >> 4;
    float acc[4][4] = {};
    for (int c = 0; c < K; ++c) {
        float a[4], b[4];
#pragma unroll
        for (int i = 0; i < 4; ++i) a[i] = As[ty * 4 + i][c];
#pragma unroll
        for (int j = 0; j < 4; ++j) b[j] = Bs[tx * 4 + j][c];
#pragma unroll
        for (int i = 0; i < 4; ++i)
#pragma unroll
            for (int j = 0; j < 4; ++j) acc[i][j] += a[i] * b[j];
    }
#pragma unroll
    for (int i = 0; i < 4; ++i)
#pragma unroll
        for (int j = 0; j < 4; ++j)
            C[(size_t)(row0 + ty * 4 + i) * N + col0 + tx * 4 + j] = alpha * acc[i][j];
}

// ================= row softmax over 1024 cols =================
__global__ __launch_bounds__(256) void row_softmax(
    const float* __restrict__ in, float* __restrict__ out, int ostride, int relu)
{
    const float* rp = in + (size_t)blockIdx.x * N_;
    float* op = out + (size_t)blockIdx.x * ostride;
    const int tid = threadIdx.x;
    float v[4];
#pragma unroll
    for (int j = 0; j < 4; ++j) {
        float x = rp[tid + 256 * j];
        if (relu) x = fmaxf(x, 0.f);
        v[j] = x;
    }
    float m = fmaxf(fmaxf(v[0], v[1]), fmaxf(v[2], v[3]));
#pragma unroll
    for (int off = 32; off > 0; off >>= 1) m = fmaxf(m, __shfl_xor(m, off));
    __shared__ float red[4], red2[4];
    int w = tid >> 6;
    if ((tid & 63) == 0) red[w] = m;
    __syncthreads();
    m = fmaxf(fmaxf(red[0], red[1]), fmaxf(red[2], red[3]));
    float s = 0.f;
#pragma unroll
    for (int j = 0; j < 4; ++j) { v[j] = expf(v[j] - m); s += v[j]; }
#pragma unroll
    for (int off = 32; off > 0; off >>= 1) s += __shfl_xor(s, off);
    if ((tid & 63) == 0) red2[w] = s;
    __syncthreads();
    s = red2[0] + red2[1] + red2[2] + red2[3];
    float inv = 1.f / s;
#pragma unroll
    for (int j = 0; j < 4; ++j) op[tid + 256 * j] = v[j] * inv;
}

// ================= WgcT[(g*64+f)][e] = Wg[g][e][f], bf16 =================
__global__ __launch_bounds__(256) void wgct_kernel(const float* __restrict__ Wg,
                                                   bf16* __restrict__ WgcT)
{
    int i = blockIdx.x * 256 + threadIdx.x;  // 16384
    int g = i >> 12, e = (i >> 6) & 63, f = i & 63;
    WgcT[(((size_t)g * 64 + f) << 6) + e] = __float2bfloat16(Wg[i]);
}

// ====== Wvc1T[(kp*64+e)][f] = Wvc1[kp][f][e], bf16, padded to 256 rows ======
__global__ __launch_bounds__(256) void wvc1t_kernel(const float* __restrict__ Wvc1,
                                                    bf16* __restrict__ WT)
{
    int i = blockIdx.x * 256 + threadIdx.x;  // 256*64
    int row = i >> 6, f = i & 63;
    float v = 0.f;
    if (row < 192) { int kp = row >> 6, e = row & 63; v = Wvc1[kp * 4096 + f * 64 + e]; }
    WT[i] = __float2bfloat16(v);
}

// ================= fp32 -> bf16 convert =================
__global__ __launch_bounds__(256) void f2b_kernel(const float* __restrict__ in,
                                                  bf16* __restrict__ out, int n)
{
    int i = blockIdx.x * 256 + threadIdx.x;
    if (i < n) out[i] = __float2bfloat16(in[i]);
}

// ================= folded gate bias =================
__global__ __launch_bounds__(256) void bias_kernel(
    const float* __restrict__ bvz, const float* __restrict__ Wmz, const float* __restrict__ bmz,
    const float* __restrict__ Wgz, const float* __restrict__ bgz, float* __restrict__ bgconst)
{
    __shared__ float bconst[64];
    const int tid = threadIdx.x;
    if (tid < 64) {
        float s = bmz[tid];
        for (int kp = 0; kp < 3; ++kp)
            for (int f = 0; f < 64; ++f) s += bvz[f] * Wmz[kp * 4096 + f * 64 + tid];
        bconst[tid] = s;
    }
    __syncthreads();
    int g = tid >> 6, fo = tid & 63;
    float s = bgz[g * 64 + fo];
    for (int e = 0; e < 64; ++e) s += bconst[e] * Wgz[g * 4096 + e * 64 + fo];
    bgconst[tid] = s;
}

// ====== VcatT build for layer 0: VcatT[(l*16+b)*64+e][kp*1024+n], bf16 ======
__global__ __launch_bounds__(256) void vcat0T_kernel(
    const float* __restrict__ hist, const float* __restrict__ Wvc0,
    bf16* __restrict__ VcatT, int l0, int LC)
{
    __shared__ float xs[3][1024];
    __shared__ float Ws[576];
    const int lb = blockIdx.x;   // l*16+b
    const int l = lb >> 4, b = lb & 15;
    const int eq = blockIdx.y;   // e quarter
    const int tid = threadIdx.x;
    for (int i = tid; i < 576; i += 256) Ws[i] = Wvc0[i];
    const float* xp = hist + ((size_t)b * L_ + (l0 + l)) * N_ * 3;
    for (int i = tid; i < 3072; i += 256) xs[i % 3][i / 3] = xp[i];
    __syncthreads();
    bf16* outb = VcatT + (size_t)lb * 64 * 3072;
#pragma unroll
    for (int kp = 0; kp < 3; ++kp)
        for (int ei = 0; ei < 16; ++ei) {
            int e = eq * 16 + ei;
            float w0 = Ws[kp * 192 + e], w1 = Ws[kp * 192 + 64 + e], w2 = Ws[kp * 192 + 128 + e];
            bf16* rp = outb + (size_t)e * 3072 + kp * 1024;
#pragma unroll
            for (int q = 0; q < 4; ++q) {
                int n = q * 256 + tid;
                rp[n] = __float2bfloat16(fmaf(xs[0][n], w0, fmaf(xs[1][n], w1, xs[2][n] * w2)));
            }
        }
}

// ================= bf16 MFMA GEMM (NT): C = A @ BT^T (+bias) =================
// A: M x K (lda), BT: N x K (ldb), C: M x N (ldc). M%128==0, N%128==0, K%64==0.
// Stores masked to gc < Nmask. OUT_BF16: 1 -> bf16 C, 0 -> fp32 C.
__device__ __forceinline__ void gload16(const bf16* g, bf16* l)
{
    __builtin_amdgcn_global_load_lds((const __attribute__((address_space(1))) void*)g,
                                     (__attribute__((address_space(3))) void*)l, 16, 0, 0);
}

template <int OUT_BF16>
__global__ __launch_bounds__(256) void gemm_mfma(
    const bf16* __restrict__ A, const bf16* __restrict__ BT, void* __restrict__ Cp,
    int M, int N, int K, int lda, int ldb, int ldc,
    const float* __restrict__ bias, int Nmask)
{
    __shared__ bf16 As[128 * 64];
    __shared__ bf16 Bs[128 * 64];
    const int tid = threadIdx.x;
    const int lane = tid & 63, w = tid >> 6;
    const int wr = w >> 1, wc = w & 1;
    const int row0 = blockIdx.y * 128, col0 = blockIdx.x * 128;

    f32x4 acc[4][4];
#pragma unroll
    for (int i = 0; i < 4; ++i)
#pragma unroll
        for (int j = 0; j < 4; ++j) acc[i][j] = (f32x4){0.f, 0.f, 0.f, 0.f};

    const int srow = w * 32 + (lane >> 3);       // staging row within tile (+i*8)
    const int scol = (lane & 7) * 8;             // staging k offset (elements)

    for (int k0 = 0; k0 < K; k0 += 64) {
#pragma unroll
        for (int i = 0; i < 4; ++i) {
            gload16(A + (size_t)(row0 + srow + i * 8) * lda + k0 + scol,
                    &As[(w * 32 + i * 8) * 64]);
            gload16(BT + (size_t)(col0 + srow + i * 8) * ldb + k0 + scol,
                    &Bs[(w * 32 + i * 8) * 64]);
        }
        __syncthreads();
#pragma unroll
        for (int kk = 0; kk < 64; kk += 32) {
            s16x8 af[4], bfr[4];
            const int ko = kk + (lane >> 4) * 8;
#pragma unroll
            for (int mi = 0; mi < 4; ++mi)
                af[mi] = *(const s16x8*)&As[(wr * 64 + mi * 16 + (lane & 15)) * 64 + ko];
#pragma unroll
            for (int ni = 0; ni < 4; ++ni)
                bfr[ni] = *(const s16x8*)&Bs[(wc * 64 + ni * 16 + (lane & 15)) * 64 + ko];
#pragma unroll
            for (int mi = 0; mi < 4; ++mi)
#pragma unroll
                for (int ni = 0; ni < 4; ++ni)
                    acc[mi][ni] = __builtin_amdgcn_mfma_f32_16x16x32_bf16(
                        af[mi], bfr[ni], acc[mi][ni], 0, 0, 0);
        }
        __syncthreads();
    }

#pragma unroll
    for (int mi = 0; mi < 4; ++mi) {
        const int gr = row0 + wr * 64 + mi * 16 + (lane >> 4) * 4;
#pragma unroll
        for (int ni = 0; ni < 4; ++ni) {
            const int gc = col0 + wc * 64 + ni * 16 + (lane & 15);
            if (gc >= Nmask) continue;
            const float bb = bias ? bias[gc] : 0.f;
#pragma unroll
            for (int j = 0; j < 4; ++j) {
                float v = acc[mi][ni][j] + bb;
                if (OUT_BF16)
                    ((bf16*)Cp)[(size_t)(gr + j) * ldc + gc] = __float2bfloat16(v);
                else
                    ((float*)Cp)[(size_t)(gr + j) * ldc + gc] = v;
            }
        }
    }
}

// ================= LSTM pointwise scan over a chunk =================
// gates rows (n*LC+l)*16+b (fp32, incl. bias), ht bf16, ct fp32.
__global__ __launch_bounds__(256) void scan_kernel(
    const float* __restrict__ gates, float* __restrict__ ct_buf,
    bf16* __restrict__ ht_out, float* __restrict__ htlast,
    int LC, int l0, int initct)
{
    const int tid = threadIdx.x;
    const int e = tid & 63;
    const int p = blockIdx.x * 4 + (tid >> 6);   // n*16+b
    const int n = p >> 4, b = p & 15;
    const size_t ci = (size_t)p * 64 + e;
    float ct = initct ? 0.f : ct_buf[ci];
    for (int l = 0; l < LC; ++l) {
        const size_t row = ((size_t)n * LC + l) * B_ + b;
        const float* g = gates + row * 256;
        float gf = g[e], gi = g[64 + e], gg = g[128 + e], go = g[192 + e];
        float f  = 1.f / (1.f + expf(-gf));
        float i_ = 1.f / (1.f + expf(-gi));
        float g_ = tanhf(gg);
        float o  = 1.f / (1.f + expf(-go));
        ct = f * ct + i_ * g_;
        float ht = o * tanhf(ct);
        if (ht_out) ht_out[row * 64 + e] = __float2bfloat16(ht);
        if (htlast && (l0 + l == L_ - 1)) htlast[ci] = ht;
    }
    ct_buf[ci] = ct;
}

// ====== transpose D (Mrows x 192, bf16) -> VcatT[(l,b,e)][kp*1024+n] ======
__global__ __launch_bounds__(256) void transposeD_kernel(
    const bf16* __restrict__ D, bf16* __restrict__ VcatT, int LC)
{
    __shared__ ushort Ts[64][66];
    const int lb = blockIdx.x, kp = blockIdx.y, nt = blockIdx.z;
    const int l = lb >> 4, b = lb & 15;
    const int n0 = nt * 64;
    const int tid = threadIdx.x;
#pragma unroll
    for (int it = 0; it < 2; ++it) {
        int idx = it * 256 + tid;
        int r = idx >> 3, u = idx & 7;
        int n = n0 + r;
        const ushort* src = (const ushort*)(D + (size_t)(((n * LC + l) << 4) + b) * 192 + kp * 64 + u * 8);
#pragma unroll
        for (int j = 0; j < 8; ++j) Ts[r][u * 8 + j] = src[j];
    }
    __syncthreads();
#pragma unroll
    for (int it = 0; it < 2; ++it) {
        int idx = it * 256 + tid;
        int e = idx >> 3, u = idx & 7;
        ushort tmp[8];
#pragma unroll
        for (int j = 0; j < 8; ++j) tmp[j] = Ts[u * 8 + j][e];
        ushort* dst = (ushort*)(VcatT + ((size_t)lb * 64 + e) * 3072 + kp * 1024 + n0 + u * 8);
        *(uint4*)dst = *(const uint4*)tmp;
    }
}

// ================= decoder =================
__global__ __launch_bounds__(256) void decoder_kernel(
    const float* __restrict__ h0, const float* __restrict__ h1,
    const float* __restrict__ Wdec, const float* __restrict__ bdec,
    const float* __restrict__ Wout, const float* __restrict__ bout,
    float* __restrict__ outp)
{
    __shared__ float Wd[12 * 2 * 64];
    __shared__ float Wo[144];
    __shared__ float bd[12], bo[12];
    const int tid = threadIdx.x;
    for (int i = tid; i < 12 * 2 * 64; i += 256) Wd[i] = Wdec[i];
    for (int i = tid; i < 144; i += 256) Wo[i] = Wout[i];
    if (tid < 12) { bd[tid] = bdec[tid]; bo[tid] = bout[tid]; }
    __syncthreads();
    const int gid = blockIdx.x * 256 + tid;   // b*1024 + n
    const int b = gid >> 10, n = gid & 1023;
    const float* h0r = h0 + ((size_t)n * 16 + b) * 64;
    const float* h1r = h1 + ((size_t)n * 16 + b) * 64;
    float dec[12];
#pragma unroll
    for (int o = 0; o < 12; ++o) dec[o] = bd[o];
    for (int e = 0; e < 64; ++e) {
        float v0 = h0r[e], v1 = h1r[e];
#pragma unroll
        for (int o = 0; o < 12; ++o) dec[o] += v0 * Wd[o * 128 + e] + v1 * Wd[o * 128 + 64 + e];
    }
#pragma unroll
    for (int o = 0; o < 12; ++o) {
        float s = bo[o];
#pragma unroll
        for (int p = 0; p < 12; ++p) s += Wo[o * 12 + p] * dec[p];
        outp[((size_t)b * 12 + o) * 1024 + n] = s;
    }
}

extern "C" void kernel_launch(void* const* d_in, const int* in_sizes, int n_in,
                              void* d_out, int out_size, void* d_ws, size_t ws_size,
                              hipStream_t stream)
{
    const float* hist = (const float*)d_in[0];
    const float* adj  = (const float*)d_in[1];
    const float* Wv0  = (const float*)d_in[2];
    const float* Wv1  = (const float*)d_in[3];
    const float* bv   = (const float*)d_in[4];
    const float* E    = (const float*)d_in[5];
    const float* Wq   = (const float*)d_in[6];
    const float* Wk   = (const float*)d_in[7];
    const float* Eg1  = (const float*)d_in[8];
    const float* Eg2  = (const float*)d_in[9];
    const float* Wmix = (const float*)d_in[10];
    const float* bmix = (const float*)d_in[11];
    const float* Wg   = (const float*)d_in[12];
    const float* bg   = (const float*)d_in[13];
    const float* Wdec = (const float*)d_in[14];
    const float* bdec = (const float*)d_in[15];
    const float* Wout = (const float*)d_in[16];
    const float* bout = (const float*)d_in[17];
    float* outp = (float*)d_out;
    (void)in_sizes; (void)n_in; (void)out_size;

    char* ws = (char*)d_ws;
    size_t off = 0;
    auto alloc = [&](size_t bytes) -> void* {
        void* p = (void*)(ws + off);
        off += (bytes + 255) & ~(size_t)255;
        return p;
    };
    float* Mcat0  = (float*)alloc((size_t)1024 * 3072 * 4);  // fp32 [M1|M2|attn]
    float* Mcat1  = (float*)alloc((size_t)1024 * 3072 * 4);
    bf16*  Mcatb0 = (bf16*)alloc((size_t)1024 * 3072 * 2);
    bf16*  Mcatb1 = (bf16*)alloc((size_t)1024 * 3072 * 2);
    float* qb     = (float*)alloc((size_t)1024 * 64 * 4);
    float* kb     = (float*)alloc((size_t)1024 * 64 * 4);
    float* logits = (float*)alloc((size_t)1024 * 1024 * 4);
    float* adp    = (float*)alloc((size_t)1024 * 1024 * 4);
    float* Wvc0   = (float*)alloc(3 * 3 * 64 * 4);           // [kp][c][e]
    float* Wvc1   = (float*)alloc(3 * 64 * 64 * 4);          // [kp][f][e]
    bf16*  Wvc1T  = (bf16*)alloc(256 * 64 * 2);              // [(kp,e) pad 256][f]
    bf16*  WgcT0  = (bf16*)alloc(256 * 64 * 2);              // [(g,f)][e]
    bf16*  WgcT1  = (bf16*)alloc(256 * 64 * 2);
    float* bgc0   = (float*)alloc(256 * 4);
    float* bgc1   = (float*)alloc(256 * 4);
    float* ct0    = (float*)alloc((size_t)N_ * B_ * 64 * 4);
    float* ct1    = (float*)alloc((size_t)N_ * B_ * 64 * 4);
    float* hl0    = (float*)alloc((size_t)N_ * B_ * 64 * 4);
    float* hl1    = (float*)alloc((size_t)N_ * B_ * 64 * 4);
    size_t fixed = off;

    // per-LC-unit scratch = 32 MiB
    static const int divs[] = {16, 12, 8, 6, 4, 3, 2, 1};
    int LC = 1;
    for (int di = 0; di < 8; ++di) {
        if (fixed + (size_t)divs[di] * 33554432ull + 65536 <= ws_size) { LC = divs[di]; break; }
    }
    bf16*  VcatT = (bf16*)alloc((size_t)LC * 6291456ull);   // (LC*1024) x 3072
    bf16*  HG    = (bf16*)alloc((size_t)LC * 2097152ull);   // 1024 x (LC*1024)
    float* gates = (float*)alloc((size_t)LC * 16777216ull); // Mrows x 256
    bf16*  Dbuf  = (bf16*)alloc((size_t)LC * 6291456ull);   // Mrows x 192
    bf16*  ht0c  = (bf16*)alloc((size_t)LC * 2097152ull);   // Mrows x 64

    dim3 blk(256);
    const float* Wvz[2] = {Wv0, Wv1};
    float* McatA[2] = {Mcat0, Mcat1};
    bf16*  McatB[2] = {Mcatb0, Mcatb1};
    bf16*  WgcT[2] = {WgcT0, WgcT1};
    float* bgc[2] = {bgc0, bgc1};

    for (int z = 0; z < 2; ++z) {
        const float* Ez = E + (size_t)z * N_ * 64;
        gemm_nn<<<dim3(1, 16), blk, 0, stream>>>(Ez, Wq + z * 4096, qb, 1024, 64, 64, 64, 64, 64, nullptr);
        gemm_nn<<<dim3(1, 16), blk, 0, stream>>>(Ez, Wk + z * 4096, kb, 1024, 64, 64, 64, 64, 64, nullptr);
        gemm_nt<<<dim3(16, 16), blk, 0, stream>>>(qb, kb, logits, 1024, 64, 0.125f);
        float* attnp = McatA[z] + 2048;  // cols 2048..3071 of Mcat (stride 3072)
        row_softmax<<<1024, blk, 0, stream>>>(logits, attnp, 3072, 0);
        gemm_nt<<<dim3(16, 16), blk, 0, stream>>>(Eg1 + z * 16384, Eg2 + z * 16384, logits, 1024, 16, 1.f);
        row_softmax<<<1024, blk, 0, stream>>>(logits, adp, 1024, 1);
        gemm_nn<<<dim3(16, 16), blk, 0, stream>>>(adj, attnp, McatA[z], 1024, 1024, 1024, 1024, 3072, 3072, nullptr);
        gemm_nn<<<dim3(16, 16), blk, 0, stream>>>(adp, attnp, McatA[z] + 1024, 1024, 1024, 1024, 1024, 3072, 3072, nullptr);
        f2b_kernel<<<12288, blk, 0, stream>>>(McatA[z], McatB[z], 1024 * 3072);
        if (z == 0) {
            for (int kp = 0; kp < 3; ++kp)
                gemm_nn<<<dim3(1, 1), blk, 0, stream>>>(Wv0, Wmix + kp * 4096,
                    Wvc0 + kp * 3 * 64, 3, 64, 64, 64, 64, 64, nullptr);
        } else {
            for (int kp = 0; kp < 3; ++kp)
                gemm_nn<<<dim3(1, 1), blk, 0, stream>>>(Wv1, Wmix + 12288 + kp * 4096,
                    Wvc1 + kp * 4096, 64, 64, 64, 64, 64, 64, nullptr);
            wvc1t_kernel<<<64, blk, 0, stream>>>(Wvc1, Wvc1T);
        }
        wgct_kernel<<<64, blk, 0, stream>>>(Wg + z * 16384, WgcT[z]);
        bias_kernel<<<1, blk, 0, stream>>>(bv + z * 64, Wmix + z * 12288, bmix + z * 64,
            Wg + z * 16384, bg + z * 256, bgc[z]);
    }

    const int nch = L_ / LC;
    const int Mrows = N_ * LC * B_;
    for (int c = 0; c < nch; ++c) {
        const int l0 = c * LC;
        // ---- layer 0 ----
        vcat0T_kernel<<<dim3(LC * 16, 4), blk, 0, stream>>>(hist, Wvc0, VcatT, l0, LC);
        gemm_mfma<1><<<dim3(LC * 8, 8), blk, 0, stream>>>(Mcatb0, VcatT, HG,
            1024, LC * 1024, 3072, 3072, 3072, LC * 1024, nullptr, LC * 1024);
        gemm_mfma<0><<<dim3(2, LC * 128), blk, 0, stream>>>(HG, WgcT0, gates,
            Mrows, 256, 64, 64, 64, 256, bgc0, 256);
        scan_kernel<<<4096, blk, 0, stream>>>(gates, ct0, ht0c, hl0, LC, l0, c == 0);
        // ---- layer 1 ----
        gemm_mfma<1><<<dim3(2, LC * 128), blk, 0, stream>>>(ht0c, Wvc1T, Dbuf,
            Mrows, 256, 64, 64, 64, 192, nullptr, 192);
        transposeD_kernel<<<dim3(LC * 16, 3, 16), blk, 0, stream>>>(Dbuf, VcatT, LC);
        gemm_mfma<1><<<dim3(LC * 8, 8), blk, 0, stream>>>(Mcatb1, VcatT, HG,
            1024, LC * 1024, 3072, 3072, 3072, LC * 1024, nullptr, LC * 1024);
        gemm_mfma<0><<<dim3(2, LC * 128), blk, 0, stream>>>(HG, WgcT1, gates,
            Mrows, 256, 64, 64, 64, 256, bgc1, 256);
        scan_kernel<<<4096, blk, 0, stream>>>(gates, ct1, nullptr, hl1, LC, l0, c == 0);
    }
    decoder_kernel<<<64, blk, 0, stream>>>(hl0, hl1, Wdec, bdec, Wout, bout, outp);
}

// Round 3
// 4077.563 us; speedup vs baseline: 6.9868x; 1.3126x over previous
//
#include <hip/hip_runtime.h>
#include <hip/hip_bf16.h>

#define B_ 16
#define L_ 96
#define N_ 1024
#define EMB_ 64

typedef __hip_bfloat16 bf16;
typedef __attribute__((ext_vector_type(4))) float f32x4;
typedef __attribute__((ext_vector_type(8))) short s16x8;

// ================= fp32 GEMM (NN), small setup mats only =================
__global__ __launch_bounds__(256) void gemm_nn(
    const float* __restrict__ A, const float* __restrict__ Bm, float* __restrict__ C,
    int M, int N, int K, int lda, int ldb, int ldc, const float* __restrict__ bias)
{
    __shared__ float As[64][17];
    __shared__ __align__(16) float Bs[16][64];
    const int tid = threadIdx.x;
    const int tx = tid & 15, ty = tid >> 4;
    const int row0 = blockIdx.y * 64, col0 = blockIdx.x * 64;
    float acc[4][4] = {};
    const int ak = tid & 15, ar = tid >> 4;
    const int bc = tid & 63, bk = tid >> 6;
    for (int k0 = 0; k0 < K; k0 += 16) {
#pragma unroll
        for (int i = 0; i < 4; ++i) {
            int r = ar + i * 16;
            int gr = row0 + r, gk = k0 + ak;
            As[r][ak] = (gr < M && gk < K) ? A[(size_t)gr * lda + gk] : 0.f;
        }
#pragma unroll
        for (int i = 0; i < 4; ++i) {
            int kk = bk + i * 4;
            int gk = k0 + kk, gc = col0 + bc;
            Bs[kk][bc] = (gk < K && gc < N) ? Bm[(size_t)gk * ldb + gc] : 0.f;
        }
        __syncthreads();
#pragma unroll
        for (int kk = 0; kk < 16; ++kk) {
            float4 b4 = *reinterpret_cast<const float4*>(&Bs[kk][tx * 4]);
            float a0 = As[ty * 4 + 0][kk];
            float a1 = As[ty * 4 + 1][kk];
            float a2 = As[ty * 4 + 2][kk];
            float a3 = As[ty * 4 + 3][kk];
            acc[0][0] += a0 * b4.x; acc[0][1] += a0 * b4.y; acc[0][2] += a0 * b4.z; acc[0][3] += a0 * b4.w;
            acc[1][0] += a1 * b4.x; acc[1][1] += a1 * b4.y; acc[1][2] += a1 * b4.z; acc[1][3] += a1 * b4.w;
            acc[2][0] += a2 * b4.x; acc[2][1] += a2 * b4.y; acc[2][2] += a2 * b4.z; acc[2][3] += a2 * b4.w;
            acc[3][0] += a3 * b4.x; acc[3][1] += a3 * b4.y; acc[3][2] += a3 * b4.z; acc[3][3] += a3 * b4.w;
        }
        __syncthreads();
    }
#pragma unroll
    for (int i = 0; i < 4; ++i) {
        int gr = row0 + ty * 4 + i;
        if (gr >= M) continue;
#pragma unroll
        for (int j = 0; j < 4; ++j) {
            int gc = col0 + tx * 4 + j;
            if (gc >= N) continue;
            float v = acc[i][j];
            if (bias) v += bias[gc];
            C[(size_t)gr * ldc + gc] = v;
        }
    }
}

// ================= fp32 GEMM (NT) small, for setup =================
__global__ __launch_bounds__(256) void gemm_nt(
    const float* __restrict__ A, const float* __restrict__ Bm, float* __restrict__ C,
    int N, int K, float alpha)
{
    __shared__ float As[64][65];
    __shared__ float Bs[64][65];
    const int tid = threadIdx.x;
    const int row0 = blockIdx.y * 64, col0 = blockIdx.x * 64;
    for (int idx = tid; idx < 64 * K; idx += 256) {
        int r = idx / K, c = idx % K;
        As[r][c] = A[(size_t)(row0 + r) * K + c];
        Bs[r][c] = Bm[(size_t)(col0 + r) * K + c];
    }
    __syncthreads();
    const int tx = tid & 15, ty = tid >> 4;
    float acc[4][4] = {};
    for (int c = 0; c < K; ++c) {
        float a[4], b[4];
#pragma unroll
        for (int i = 0; i < 4; ++i) a[i] = As[ty * 4 + i][c];
#pragma unroll
        for (int j = 0; j < 4; ++j) b[j] = Bs[tx * 4 + j][c];
#pragma unroll
        for (int i = 0; i < 4; ++i)
#pragma unroll
            for (int j = 0; j < 4; ++j) acc[i][j] += a[i] * b[j];
    }
#pragma unroll
    for (int i = 0; i < 4; ++i)
#pragma unroll
        for (int j = 0; j < 4; ++j)
            C[(size_t)(row0 + ty * 4 + i) * N + col0 + tx * 4 + j] = alpha * acc[i][j];
}

// ======= row softmax over 1024 cols; optional fp32 and/or bf16 outputs =======
__global__ __launch_bounds__(256) void row_softmax(
    const float* __restrict__ in, float* __restrict__ out32, int os32,
    bf16* __restrict__ out16, int os16, int relu)
{
    const float* rp = in + (size_t)blockIdx.x * N_;
    const int tid = threadIdx.x;
    float v[4];
#pragma unroll
    for (int j = 0; j < 4; ++j) {
        float x = rp[tid + 256 * j];
        if (relu) x = fmaxf(x, 0.f);
        v[j] = x;
    }
    float m = fmaxf(fmaxf(v[0], v[1]), fmaxf(v[2], v[3]));
#pragma unroll
    for (int off = 32; off > 0; off >>= 1) m = fmaxf(m, __shfl_xor(m, off));
    __shared__ float red[4], red2[4];
    int w = tid >> 6;
    if ((tid & 63) == 0) red[w] = m;
    __syncthreads();
    m = fmaxf(fmaxf(red[0], red[1]), fmaxf(red[2], red[3]));
    float s = 0.f;
#pragma unroll
    for (int j = 0; j < 4; ++j) { v[j] = __expf(v[j] - m); s += v[j]; }
#pragma unroll
    for (int off = 32; off > 0; off >>= 1) s += __shfl_xor(s, off);
    if ((tid & 63) == 0) red2[w] = s;
    __syncthreads();
    s = red2[0] + red2[1] + red2[2] + red2[3];
    float inv = 1.f / s;
#pragma unroll
    for (int j = 0; j < 4; ++j) {
        float r = v[j] * inv;
        if (out32) out32[(size_t)blockIdx.x * os32 + tid + 256 * j] = r;
        if (out16) out16[(size_t)blockIdx.x * os16 + tid + 256 * j] = __float2bfloat16(r);
    }
}

// ======= transpose 1024x1024 fp32 -> bf16 (out[r][c] = in[c][r]) =======
__global__ __launch_bounds__(256) void transpose_f2b(
    const float* __restrict__ in, bf16* __restrict__ out)
{
    __shared__ float t[64][65];
    const int cx = blockIdx.x, cy = blockIdx.y;
    const int tid = threadIdx.x;
#pragma unroll
    for (int k = 0; k < 16; ++k) {
        int idx = k * 256 + tid;
        int r = idx >> 6, c = idx & 63;
        t[r][c] = in[(size_t)(cy * 64 + r) * 1024 + cx * 64 + c];
    }
    __syncthreads();
#pragma unroll
    for (int k = 0; k < 16; ++k) {
        int idx = k * 256 + tid;
        int r = idx >> 6, c = idx & 63;
        out[(size_t)(cx * 64 + r) * 1024 + cy * 64 + c] = __float2bfloat16(t[c][r]);
    }
}

// ================= WgcT[(g*64+f)][e] = Wg[g][e][f], bf16 =================
__global__ __launch_bounds__(256) void wgct_kernel(const float* __restrict__ Wg,
                                                   bf16* __restrict__ WgcT)
{
    int i = blockIdx.x * 256 + threadIdx.x;  // 16384
    int g = i >> 12, e = (i >> 6) & 63, f = i & 63;
    WgcT[(((size_t)g * 64 + f) << 6) + e] = __float2bfloat16(Wg[i]);
}

// ====== Wvc1T[(kp*64+e)][f] = Wvc1[kp][f][e], bf16, padded to 256 rows ======
__global__ __launch_bounds__(256) void wvc1t_kernel(const float* __restrict__ Wvc1,
                                                    bf16* __restrict__ WT)
{
    int i = blockIdx.x * 256 + threadIdx.x;  // 256*64
    int row = i >> 6, f = i & 63;
    float v = 0.f;
    if (row < 192) { int kp = row >> 6, e = row & 63; v = Wvc1[kp * 4096 + f * 64 + e]; }
    WT[i] = __float2bfloat16(v);
}

// ================= fp32 -> bf16 convert =================
__global__ __launch_bounds__(256) void f2b_kernel(const float* __restrict__ in,
                                                  bf16* __restrict__ out, int n)
{
    int i = blockIdx.x * 256 + threadIdx.x;
    if (i < n) out[i] = __float2bfloat16(in[i]);
}

// ================= folded gate bias =================
__global__ __launch_bounds__(256) void bias_kernel(
    const float* __restrict__ bvz, const float* __restrict__ Wmz, const float* __restrict__ bmz,
    const float* __restrict__ Wgz, const float* __restrict__ bgz, float* __restrict__ bgconst)
{
    __shared__ float bconst[64];
    const int tid = threadIdx.x;
    if (tid < 64) {
        float s = bmz[tid];
        for (int kp = 0; kp < 3; ++kp)
            for (int f = 0; f < 64; ++f) s += bvz[f] * Wmz[kp * 4096 + f * 64 + tid];
        bconst[tid] = s;
    }
    __syncthreads();
    int g = tid >> 6, fo = tid & 63;
    float s = bgz[g * 64 + fo];
    for (int e = 0; e < 64; ++e) s += bconst[e] * Wgz[g * 4096 + e * 64 + fo];
    bgconst[tid] = s;
}

// ====== VcatT build for layer 0: VcatT[(l*16+b)*64+e][kp*1024+n], bf16 ======
__global__ __launch_bounds__(256) void vcat0T_kernel(
    const float* __restrict__ hist, const float* __restrict__ Wvc0,
    bf16* __restrict__ VcatT, int l0, int LC)
{
    __shared__ float xs[3][1024];
    __shared__ float Ws[576];
    const int lb = blockIdx.x;   // l*16+b
    const int l = lb >> 4, b = lb & 15;
    const int eq = blockIdx.y;   // e quarter
    const int tid = threadIdx.x;
    for (int i = tid; i < 576; i += 256) Ws[i] = Wvc0[i];
    const float* xp = hist + ((size_t)b * L_ + (l0 + l)) * N_ * 3;
    for (int i = tid; i < 3072; i += 256) xs[i % 3][i / 3] = xp[i];
    __syncthreads();
    bf16* outb = VcatT + (size_t)lb * 64 * 3072;
#pragma unroll
    for (int kp = 0; kp < 3; ++kp)
        for (int ei = 0; ei < 16; ++ei) {
            int e = eq * 16 + ei;
            float w0 = Ws[kp * 192 + e], w1 = Ws[kp * 192 + 64 + e], w2 = Ws[kp * 192 + 128 + e];
            bf16* rp = outb + (size_t)e * 3072 + kp * 1024;
#pragma unroll
            for (int q = 0; q < 4; ++q) {
                int n = q * 256 + tid;
                rp[n] = __float2bfloat16(fmaf(xs[0][n], w0, fmaf(xs[1][n], w1, xs[2][n] * w2)));
            }
        }
}

// ================= bf16 MFMA GEMM (NT): C = A @ BT^T =================
__device__ __forceinline__ void gload16(const bf16* g, bf16* l)
{
    __builtin_amdgcn_global_load_lds((const __attribute__((address_space(1))) void*)g,
                                     (__attribute__((address_space(3))) void*)l, 16, 0, 0);
}

template <int OUT_BF16>
__global__ __launch_bounds__(256) void gemm_mfma(
    const bf16* __restrict__ A, const bf16* __restrict__ BT, void* __restrict__ Cp,
    int M, int N, int K, int lda, int ldb, int ldc,
    const float* __restrict__ bias, int Nmask)
{
    __shared__ bf16 As[128 * 64];
    __shared__ bf16 Bs[128 * 64];
    const int tid = threadIdx.x;
    const int lane = tid & 63, w = tid >> 6;
    const int wr = w >> 1, wc = w & 1;
    const int row0 = blockIdx.y * 128, col0 = blockIdx.x * 128;

    f32x4 acc[4][4];
#pragma unroll
    for (int i = 0; i < 4; ++i)
#pragma unroll
        for (int j = 0; j < 4; ++j) acc[i][j] = (f32x4){0.f, 0.f, 0.f, 0.f};

    const int srow = w * 32 + (lane >> 3);
    const int scol = (lane & 7) * 8;

    for (int k0 = 0; k0 < K; k0 += 64) {
#pragma unroll
        for (int i = 0; i < 4; ++i) {
            gload16(A + (size_t)(row0 + srow + i * 8) * lda + k0 + scol,
                    &As[(w * 32 + i * 8) * 64]);
            gload16(BT + (size_t)(col0 + srow + i * 8) * ldb + k0 + scol,
                    &Bs[(w * 32 + i * 8) * 64]);
        }
        __syncthreads();
#pragma unroll
        for (int kk = 0; kk < 64; kk += 32) {
            s16x8 af[4], bfr[4];
            const int ko = kk + (lane >> 4) * 8;
#pragma unroll
            for (int mi = 0; mi < 4; ++mi)
                af[mi] = *(const s16x8*)&As[(wr * 64 + mi * 16 + (lane & 15)) * 64 + ko];
#pragma unroll
            for (int ni = 0; ni < 4; ++ni)
                bfr[ni] = *(const s16x8*)&Bs[(wc * 64 + ni * 16 + (lane & 15)) * 64 + ko];
#pragma unroll
            for (int mi = 0; mi < 4; ++mi)
#pragma unroll
                for (int ni = 0; ni < 4; ++ni)
                    acc[mi][ni] = __builtin_amdgcn_mfma_f32_16x16x32_bf16(
                        af[mi], bfr[ni], acc[mi][ni], 0, 0, 0);
        }
        __syncthreads();
    }

#pragma unroll
    for (int mi = 0; mi < 4; ++mi) {
        const int gr = row0 + wr * 64 + mi * 16 + (lane >> 4) * 4;
#pragma unroll
        for (int ni = 0; ni < 4; ++ni) {
            const int gc = col0 + wc * 64 + ni * 16 + (lane & 15);
            if (gc >= Nmask) continue;
            const float bb = bias ? bias[gc] : 0.f;
#pragma unroll
            for (int j = 0; j < 4; ++j) {
                float v = acc[mi][ni][j] + bb;
                if (OUT_BF16)
                    ((bf16*)Cp)[(size_t)(gr + j) * ldc + gc] = __float2bfloat16(v);
                else
                    ((float*)Cp)[(size_t)(gr + j) * ldc + gc] = v;
            }
        }
    }
}

// ========== fused gates GEMM (16x256,K=64 MFMA per step) + LSTM scan ==========
// Block = one node n. HG rows for n are contiguous: HG + n*LC*1024, row (l*16+b), col e.
// WgcT: 256 x 64 (row g*64+f, col e). ct layout (n*16+b)*64+f.
__global__ __launch_bounds__(256) void fused_gates_scan(
    const bf16* __restrict__ HG, const bf16* __restrict__ WgcT,
    const float* __restrict__ bgc, float* __restrict__ ct_buf,
    bf16* __restrict__ ht_out, float* __restrict__ htlast,
    int LC, int l0, int initct)
{
    __shared__ bf16 As[192 * 64];     // up to LC=12 staged HG rows
    __shared__ bf16 Bs[256 * 64];     // WgcT
    __shared__ float gbuf[16 * 256];  // one l-step of gates
    __shared__ float bgs[256];
    const int tid = threadIdx.x;
    const int lane = tid & 63, w = tid >> 6;
    const int n = blockIdx.x;

    // stage WgcT: 16384 elems, 2048/round
#pragma unroll
    for (int r = 0; r < 8; ++r)
        gload16(WgcT + r * 2048 + w * 512 + lane * 8, &Bs[r * 2048 + w * 512]);
    // stage HG rows for this n: LC*1024 elems
    const bf16* HGn = HG + (size_t)n * LC * 1024;
    const int totA = LC * 1024;
    for (int r = 0; r * 2048 < totA; ++r) {
        int seg = r * 2048 + w * 512;
        if (seg < totA) gload16(HGn + seg + lane * 8, &As[seg]);
    }
    bgs[tid] = bgc[tid];
    __syncthreads();

    float ct[4];
    const size_t cbase = (size_t)n * 1024;
#pragma unroll
    for (int it = 0; it < 4; ++it)
        ct[it] = initct ? 0.f : ct_buf[cbase + it * 256 + tid];

    const int ar = (lane & 15), ak = (lane >> 4) * 8;
    for (int l = 0; l < LC; ++l) {
        f32x4 acc[4];
#pragma unroll
        for (int ni = 0; ni < 4; ++ni) acc[ni] = (f32x4){0.f, 0.f, 0.f, 0.f};
#pragma unroll
        for (int kk = 0; kk < 64; kk += 32) {
            s16x8 af = *(const s16x8*)&As[(l * 16 + ar) * 64 + ak + kk];
#pragma unroll
            for (int ni = 0; ni < 4; ++ni) {
                s16x8 bf = *(const s16x8*)&Bs[(w * 64 + ni * 16 + ar) * 64 + ak + kk];
                acc[ni] = __builtin_amdgcn_mfma_f32_16x16x32_bf16(af, bf, acc[ni], 0, 0, 0);
            }
        }
        __syncthreads();   // previous scan's gbuf reads complete
#pragma unroll
        for (int ni = 0; ni < 4; ++ni)
#pragma unroll
            for (int j = 0; j < 4; ++j)
                gbuf[((lane >> 4) * 4 + j) * 256 + w * 64 + ni * 16 + (lane & 15)] = acc[ni][j];
        __syncthreads();
        // scan step
        const size_t hbase = ((size_t)n * LC + l) * 1024;
        const bool last = (l0 + l == L_ - 1);
#pragma unroll
        for (int it = 0; it < 4; ++it) {
            const int flat = it * 256 + tid;
            const int bi = (flat >> 6) * 256 + (flat & 63);
            const int f = flat & 63;
            float xf = gbuf[bi] + bgs[f];
            float xi = gbuf[bi + 64] + bgs[64 + f];
            float xg = gbuf[bi + 128] + bgs[128 + f];
            float xo = gbuf[bi + 192] + bgs[192 + f];
            float fg = 1.f / (1.f + __expf(-xf));
            float ig = 1.f / (1.f + __expf(-xi));
            float gg = 2.f / (1.f + __expf(-2.f * xg)) - 1.f;
            float og = 1.f / (1.f + __expf(-xo));
            ct[it] = fg * ct[it] + ig * gg;
            float ht = og * (2.f / (1.f + __expf(-2.f * ct[it])) - 1.f);
            if (ht_out) ht_out[hbase + flat] = __float2bfloat16(ht);
            if (htlast && last) htlast[cbase + flat] = ht;
        }
    }
#pragma unroll
    for (int it = 0; it < 4; ++it)
        ct_buf[cbase + it * 256 + tid] = ct[it];
}

// ====== transpose D (Mrows x 192, bf16) -> VcatT[(l,b,e)][kp*1024+n] ======
__global__ __launch_bounds__(256) void transposeD_kernel(
    const bf16* __restrict__ D, bf16* __restrict__ VcatT, int LC)
{
    __shared__ ushort Ts[64][66];
    const int lb = blockIdx.x, kp = blockIdx.y, nt = blockIdx.z;
    const int l = lb >> 4, b = lb & 15;
    const int n0 = nt * 64;
    const int tid = threadIdx.x;
#pragma unroll
    for (int it = 0; it < 2; ++it) {
        int idx = it * 256 + tid;
        int r = idx >> 3, u = idx & 7;
        int n = n0 + r;
        const ushort* src = (const ushort*)(D + (size_t)(((n * LC + l) << 4) + b) * 192 + kp * 64 + u * 8);
#pragma unroll
        for (int j = 0; j < 8; ++j) Ts[r][u * 8 + j] = src[j];
    }
    __syncthreads();
#pragma unroll
    for (int it = 0; it < 2; ++it) {
        int idx = it * 256 + tid;
        int e = idx >> 3, u = idx & 7;
        ushort tmp[8];
#pragma unroll
        for (int j = 0; j < 8; ++j) tmp[j] = Ts[u * 8 + j][e];
        ushort* dst = (ushort*)(VcatT + ((size_t)lb * 64 + e) * 3072 + kp * 1024 + n0 + u * 8);
        *(uint4*)dst = *(const uint4*)tmp;
    }
}

// ================= decoder =================
__global__ __launch_bounds__(256) void decoder_kernel(
    const float* __restrict__ h0, const float* __restrict__ h1,
    const float* __restrict__ Wdec, const float* __restrict__ bdec,
    const float* __restrict__ Wout, const float* __restrict__ bout,
    float* __restrict__ outp)
{
    __shared__ float Wd[12 * 2 * 64];
    __shared__ float Wo[144];
    __shared__ float bd[12], bo[12];
    const int tid = threadIdx.x;
    for (int i = tid; i < 12 * 2 * 64; i += 256) Wd[i] = Wdec[i];
    for (int i = tid; i < 144; i += 256) Wo[i] = Wout[i];
    if (tid < 12) { bd[tid] = bdec[tid]; bo[tid] = bout[tid]; }
    __syncthreads();
    const int gid = blockIdx.x * 256 + tid;   // b*1024 + n
    const int b = gid >> 10, n = gid & 1023;
    const float* h0r = h0 + ((size_t)n * 16 + b) * 64;
    const float* h1r = h1 + ((size_t)n * 16 + b) * 64;
    float dec[12];
#pragma unroll
    for (int o = 0; o < 12; ++o) dec[o] = bd[o];
    for (int e = 0; e < 64; ++e) {
        float v0 = h0r[e], v1 = h1r[e];
#pragma unroll
        for (int o = 0; o < 12; ++o) dec[o] += v0 * Wd[o * 128 + e] + v1 * Wd[o * 128 + 64 + e];
    }
#pragma unroll
    for (int o = 0; o < 12; ++o) {
        float s = bo[o];
#pragma unroll
        for (int p = 0; p < 12; ++p) s += Wo[o * 12 + p] * dec[p];
        outp[((size_t)b * 12 + o) * 1024 + n] = s;
    }
}

extern "C" void kernel_launch(void* const* d_in, const int* in_sizes, int n_in,
                              void* d_out, int out_size, void* d_ws, size_t ws_size,
                              hipStream_t stream)
{
    const float* hist = (const float*)d_in[0];
    const float* adj  = (const float*)d_in[1];
    const float* Wv0  = (const float*)d_in[2];
    const float* Wv1  = (const float*)d_in[3];
    const float* bv   = (const float*)d_in[4];
    const float* E    = (const float*)d_in[5];
    const float* Wq   = (const float*)d_in[6];
    const float* Wk   = (const float*)d_in[7];
    const float* Eg1  = (const float*)d_in[8];
    const float* Eg2  = (const float*)d_in[9];
    const float* Wmix = (const float*)d_in[10];
    const float* bmix = (const float*)d_in[11];
    const float* Wg   = (const float*)d_in[12];
    const float* bg   = (const float*)d_in[13];
    const float* Wdec = (const float*)d_in[14];
    const float* bdec = (const float*)d_in[15];
    const float* Wout = (const float*)d_in[16];
    const float* bout = (const float*)d_in[17];
    float* outp = (float*)d_out;
    (void)in_sizes; (void)n_in; (void)out_size;

    char* ws = (char*)d_ws;
    size_t off = 0;
    auto alloc = [&](size_t bytes) -> void* {
        void* p = (void*)(ws + off);
        off += (bytes + 255) & ~(size_t)255;
        return p;
    };
    bf16*  Mcatb0 = (bf16*)alloc((size_t)1024 * 3072 * 2);   // [M1|M2|attn] bf16
    bf16*  Mcatb1 = (bf16*)alloc((size_t)1024 * 3072 * 2);
    float* attnf  = (float*)alloc((size_t)1024 * 1024 * 4);
    bf16*  attnT  = (bf16*)alloc((size_t)1024 * 1024 * 2);
    bf16*  adjb   = (bf16*)alloc((size_t)1024 * 1024 * 2);
    bf16*  adpb   = (bf16*)alloc((size_t)1024 * 1024 * 2);
    float* qb     = (float*)alloc((size_t)1024 * 64 * 4);
    float* kb     = (float*)alloc((size_t)1024 * 64 * 4);
    float* logits = (float*)alloc((size_t)1024 * 1024 * 4);
    float* Wvc0   = (float*)alloc(3 * 3 * 64 * 4);           // [kp][c][e]
    float* Wvc1   = (float*)alloc(3 * 64 * 64 * 4);          // [kp][f][e]
    bf16*  Wvc1T  = (bf16*)alloc(256 * 64 * 2);
    bf16*  WgcT0  = (bf16*)alloc(256 * 64 * 2);
    bf16*  WgcT1  = (bf16*)alloc(256 * 64 * 2);
    float* bgc0   = (float*)alloc(256 * 4);
    float* bgc1   = (float*)alloc(256 * 4);
    float* ct0    = (float*)alloc((size_t)N_ * B_ * 64 * 4);
    float* ct1    = (float*)alloc((size_t)N_ * B_ * 64 * 4);
    float* hl0    = (float*)alloc((size_t)N_ * B_ * 64 * 4);
    float* hl1    = (float*)alloc((size_t)N_ * B_ * 64 * 4);
    size_t fixed = off;

    // per-LC-unit scratch: VcatT 6MiB + HG 2MiB + Dbuf 6MiB + ht0c 2MiB = 16MiB
    static const int divs[] = {12, 8, 6, 4, 2, 1};
    int LC = 1;
    for (int di = 0; di < 6; ++di) {
        if (fixed + (size_t)divs[di] * 16777216ull + 65536 <= ws_size) { LC = divs[di]; break; }
    }
    bf16*  VcatT = (bf16*)alloc((size_t)LC * 6291456ull);   // (LC*1024) x 3072
    bf16*  HG    = (bf16*)alloc((size_t)LC * 2097152ull);   // 1024 x (LC*1024)
    bf16*  Dbuf  = (bf16*)alloc((size_t)LC * 6291456ull);   // Mrows x 192
    bf16*  ht0c  = (bf16*)alloc((size_t)LC * 2097152ull);   // Mrows x 64

    dim3 blk(256);
    bf16*  McatB[2] = {Mcatb0, Mcatb1};
    bf16*  WgcT[2] = {WgcT0, WgcT1};
    float* bgc[2] = {bgc0, bgc1};

    f2b_kernel<<<4096, blk, 0, stream>>>(adj, adjb, 1024 * 1024);
    for (int z = 0; z < 2; ++z) {
        const float* Ez = E + (size_t)z * N_ * 64;
        gemm_nn<<<dim3(1, 16), blk, 0, stream>>>(Ez, Wq + z * 4096, qb, 1024, 64, 64, 64, 64, 64, nullptr);
        gemm_nn<<<dim3(1, 16), blk, 0, stream>>>(Ez, Wk + z * 4096, kb, 1024, 64, 64, 64, 64, 64, nullptr);
        gemm_nt<<<dim3(16, 16), blk, 0, stream>>>(qb, kb, logits, 1024, 64, 0.125f);
        // attn -> fp32 (for transpose) + bf16 into Mcatb cols 2048..3071
        row_softmax<<<1024, blk, 0, stream>>>(logits, attnf, 1024, McatB[z] + 2048, 3072, 0);
        transpose_f2b<<<dim3(16, 16), blk, 0, stream>>>(attnf, attnT);
        gemm_nt<<<dim3(16, 16), blk, 0, stream>>>(Eg1 + z * 16384, Eg2 + z * 16384, logits, 1024, 16, 1.f);
        row_softmax<<<1024, blk, 0, stream>>>(logits, nullptr, 0, adpb, 1024, 1);
        // M1 = adj@attn, M2 = adp@attn  via bf16 MFMA (C = A @ attnT^T)
        gemm_mfma<1><<<dim3(8, 8), blk, 0, stream>>>(adjb, attnT, McatB[z],
            1024, 1024, 1024, 1024, 1024, 3072, nullptr, 1024);
        gemm_mfma<1><<<dim3(8, 8), blk, 0, stream>>>(adpb, attnT, McatB[z] + 1024,
            1024, 1024, 1024, 1024, 1024, 3072, nullptr, 1024);
        if (z == 0) {
            for (int kp = 0; kp < 3; ++kp)
                gemm_nn<<<dim3(1, 1), blk, 0, stream>>>(Wv0, Wmix + kp * 4096,
                    Wvc0 + kp * 3 * 64, 3, 64, 64, 64, 64, 64, nullptr);
        } else {
            for (int kp = 0; kp < 3; ++kp)
                gemm_nn<<<dim3(1, 1), blk, 0, stream>>>(Wv1, Wmix + 12288 + kp * 4096,
                    Wvc1 + kp * 4096, 64, 64, 64, 64, 64, 64, nullptr);
            wvc1t_kernel<<<64, blk, 0, stream>>>(Wvc1, Wvc1T);
        }
        wgct_kernel<<<64, blk, 0, stream>>>(Wg + z * 16384, WgcT[z]);
        bias_kernel<<<1, blk, 0, stream>>>(bv + z * 64, Wmix + z * 12288, bmix + z * 64,
            Wg + z * 16384, bg + z * 256, bgc[z]);
    }

    const int nch = L_ / LC;
    const int Mrows = N_ * LC * B_;
    for (int c = 0; c < nch; ++c) {
        const int l0 = c * LC;
        // ---- layer 0 ----
        vcat0T_kernel<<<dim3(LC * 16, 4), blk, 0, stream>>>(hist, Wvc0, VcatT, l0, LC);
        gemm_mfma<1><<<dim3(LC * 8, 8), blk, 0, stream>>>(Mcatb0, VcatT, HG,
            1024, LC * 1024, 3072, 3072, 3072, LC * 1024, nullptr, LC * 1024);
        fused_gates_scan<<<1024, blk, 0, stream>>>(HG, WgcT0, bgc0, ct0,
            ht0c, hl0, LC, l0, c == 0);
        // ---- layer 1 ----
        gemm_mfma<1><<<dim3(2, LC * 128), blk, 0, stream>>>(ht0c, Wvc1T, Dbuf,
            Mrows, 256, 64, 64, 64, 192, nullptr, 192);
        transposeD_kernel<<<dim3(LC * 16, 3, 16), blk, 0, stream>>>(Dbuf, VcatT, LC);
        gemm_mfma<1><<<dim3(LC * 8, 8), blk, 0, stream>>>(Mcatb1, VcatT, HG,
            1024, LC * 1024, 3072, 3072, 3072, LC * 1024, nullptr, LC * 1024);
        fused_gates_scan<<<1024, blk, 0, stream>>>(HG, WgcT1, bgc1, ct1,
            nullptr, hl1, LC, l0, c == 0);
    }
    decoder_kernel<<<64, blk, 0, stream>>>(hl0, hl1, Wdec, bdec, Wout, bout, outp);
}

// Round 4
// 2570.346 us; speedup vs baseline: 11.0837x; 1.5864x over previous
//
#include <hip/hip_runtime.h>
#include <hip/hip_bf16.h>

#define B_ 16
#define L_ 96
#define N_ 1024
#define EMB_ 64

typedef __hip_bfloat16 bf16;
typedef __attribute__((ext_vector_type(4))) float f32x4;
typedef __attribute__((ext_vector_type(8))) short s16x8;

// ================= fp32 GEMM (NN), small setup mats only =================
__global__ __launch_bounds__(256) void gemm_nn(
    const float* __restrict__ A, const float* __restrict__ Bm, float* __restrict__ C,
    int M, int N, int K, int lda, int ldb, int ldc, const float* __restrict__ bias)
{
    __shared__ float As[64][17];
    __shared__ __align__(16) float Bs[16][64];
    const int tid = threadIdx.x;
    const int tx = tid & 15, ty = tid >> 4;
    const int row0 = blockIdx.y * 64, col0 = blockIdx.x * 64;
    float acc[4][4] = {};
    const int ak = tid & 15, ar = tid >> 4;
    const int bc = tid & 63, bk = tid >> 6;
    for (int k0 = 0; k0 < K; k0 += 16) {
#pragma unroll
        for (int i = 0; i < 4; ++i) {
            int r = ar + i * 16;
            int gr = row0 + r, gk = k0 + ak;
            As[r][ak] = (gr < M && gk < K) ? A[(size_t)gr * lda + gk] : 0.f;
        }
#pragma unroll
        for (int i = 0; i < 4; ++i) {
            int kk = bk + i * 4;
            int gk = k0 + kk, gc = col0 + bc;
            Bs[kk][bc] = (gk < K && gc < N) ? Bm[(size_t)gk * ldb + gc] : 0.f;
        }
        __syncthreads();
#pragma unroll
        for (int kk = 0; kk < 16; ++kk) {
            float4 b4 = *reinterpret_cast<const float4*>(&Bs[kk][tx * 4]);
            float a0 = As[ty * 4 + 0][kk];
            float a1 = As[ty * 4 + 1][kk];
            float a2 = As[ty * 4 + 2][kk];
            float a3 = As[ty * 4 + 3][kk];
            acc[0][0] += a0 * b4.x; acc[0][1] += a0 * b4.y; acc[0][2] += a0 * b4.z; acc[0][3] += a0 * b4.w;
            acc[1][0] += a1 * b4.x; acc[1][1] += a1 * b4.y; acc[1][2] += a1 * b4.z; acc[1][3] += a1 * b4.w;
            acc[2][0] += a2 * b4.x; acc[2][1] += a2 * b4.y; acc[2][2] += a2 * b4.z; acc[2][3] += a2 * b4.w;
            acc[3][0] += a3 * b4.x; acc[3][1] += a3 * b4.y; acc[3][2] += a3 * b4.z; acc[3][3] += a3 * b4.w;
        }
        __syncthreads();
    }
#pragma unroll
    for (int i = 0; i < 4; ++i) {
        int gr = row0 + ty * 4 + i;
        if (gr >= M) continue;
#pragma unroll
        for (int j = 0; j < 4; ++j) {
            int gc = col0 + tx * 4 + j;
            if (gc >= N) continue;
            float v = acc[i][j];
            if (bias) v += bias[gc];
            C[(size_t)gr * ldc + gc] = v;
        }
    }
}

// ================= fp32 GEMM (NT) small, for setup =================
__global__ __launch_bounds__(256) void gemm_nt(
    const float* __restrict__ A, const float* __restrict__ Bm, float* __restrict__ C,
    int N, int K, float alpha)
{
    __shared__ float As[64][65];
    __shared__ float Bs[64][65];
    const int tid = threadIdx.x;
    const int row0 = blockIdx.y * 64, col0 = blockIdx.x * 64;
    for (int idx = tid; idx < 64 * K; idx += 256) {
        int r = idx / K, c = idx % K;
        As[r][c] = A[(size_t)(row0 + r) * K + c];
        Bs[r][c] = Bm[(size_t)(col0 + r) * K + c];
    }
    __syncthreads();
    const int tx = tid & 15, ty = tid >> 4;
    float acc[4][4] = {};
    for (int c = 0; c < K; ++c) {
        float a[4], b[4];
#pragma unroll
        for (int i = 0; i < 4; ++i) a[i] = As[ty * 4 + i][c];
#pragma unroll
        for (int j = 0; j < 4; ++j) b[j] = Bs[tx * 4 + j][c];
#pragma unroll
        for (int i = 0; i < 4; ++i)
#pragma unroll
            for (int j = 0; j < 4; ++j) acc[i][j] += a[i] * b[j];
    }
#pragma unroll
    for (int i = 0; i < 4; ++i)
#pragma unroll
        for (int j = 0; j < 4; ++j)
            C[(size_t)(row0 + ty * 4 + i) * N + col0 + tx * 4 + j] = alpha * acc[i][j];
}

// ======= row softmax over 1024 cols; optional fp32 and/or bf16 outputs =======
__global__ __launch_bounds__(256) void row_softmax(
    const float* __restrict__ in, float* __restrict__ out32, int os32,
    bf16* __restrict__ out16, int os16, int relu)
{
    const float* rp = in + (size_t)blockIdx.x * N_;
    const int tid = threadIdx.x;
    float v[4];
#pragma unroll
    for (int j = 0; j < 4; ++j) {
        float x = rp[tid + 256 * j];
        if (relu) x = fmaxf(x, 0.f);
        v[j] = x;
    }
    float m = fmaxf(fmaxf(v[0], v[1]), fmaxf(v[2], v[3]));
#pragma unroll
    for (int off = 32; off > 0; off >>= 1) m = fmaxf(m, __shfl_xor(m, off));
    __shared__ float red[4], red2[4];
    int w = tid >> 6;
    if ((tid & 63) == 0) red[w] = m;
    __syncthreads();
    m = fmaxf(fmaxf(red[0], red[1]), fmaxf(red[2], red[3]));
    float s = 0.f;
#pragma unroll
    for (int j = 0; j < 4; ++j) { v[j] = __expf(v[j] - m); s += v[j]; }
#pragma unroll
    for (int off = 32; off > 0; off >>= 1) s += __shfl_xor(s, off);
    if ((tid & 63) == 0) red2[w] = s;
    __syncthreads();
    s = red2[0] + red2[1] + red2[2] + red2[3];
    float inv = 1.f / s;
#pragma unroll
    for (int j = 0; j < 4; ++j) {
        float r = v[j] * inv;
        if (out32) out32[(size_t)blockIdx.x * os32 + tid + 256 * j] = r;
        if (out16) out16[(size_t)blockIdx.x * os16 + tid + 256 * j] = __float2bfloat16(r);
    }
}

// ======= transpose 1024x1024 fp32 -> bf16 (out[r][c] = in[c][r]) =======
__global__ __launch_bounds__(256) void transpose_f2b(
    const float* __restrict__ in, bf16* __restrict__ out)
{
    __shared__ float t[64][65];
    const int cx = blockIdx.x, cy = blockIdx.y;
    const int tid = threadIdx.x;
#pragma unroll
    for (int k = 0; k < 16; ++k) {
        int idx = k * 256 + tid;
        int r = idx >> 6, c = idx & 63;
        t[r][c] = in[(size_t)(cy * 64 + r) * 1024 + cx * 64 + c];
    }
    __syncthreads();
#pragma unroll
    for (int k = 0; k < 16; ++k) {
        int idx = k * 256 + tid;
        int r = idx >> 6, c = idx & 63;
        out[(size_t)(cx * 64 + r) * 1024 + cy * 64 + c] = __float2bfloat16(t[c][r]);
    }
}

// ================= WgcT[(g*64+f)][e] = Wg[g][e][f], bf16 =================
__global__ __launch_bounds__(256) void wgct_kernel(const float* __restrict__ Wg,
                                                   bf16* __restrict__ WgcT)
{
    int i = blockIdx.x * 256 + threadIdx.x;  // 16384
    int g = i >> 12, e = (i >> 6) & 63, f = i & 63;
    WgcT[(((size_t)g * 64 + f) << 6) + e] = __float2bfloat16(Wg[i]);
}

// ====== Wvc1T[(kp*64+e)][f] = Wvc1[kp][f][e], bf16, padded to 256 rows ======
__global__ __launch_bounds__(256) void wvc1t_kernel(const float* __restrict__ Wvc1,
                                                    bf16* __restrict__ WT)
{
    int i = blockIdx.x * 256 + threadIdx.x;  // 256*64
    int row = i >> 6, f = i & 63;
    float v = 0.f;
    if (row < 192) { int kp = row >> 6, e = row & 63; v = Wvc1[kp * 4096 + f * 64 + e]; }
    WT[i] = __float2bfloat16(v);
}

// ================= fp32 -> bf16 convert =================
__global__ __launch_bounds__(256) void f2b_kernel(const float* __restrict__ in,
                                                  bf16* __restrict__ out, int n)
{
    int i = blockIdx.x * 256 + threadIdx.x;
    if (i < n) out[i] = __float2bfloat16(in[i]);
}

// ================= folded gate bias =================
__global__ __launch_bounds__(256) void bias_kernel(
    const float* __restrict__ bvz, const float* __restrict__ Wmz, const float* __restrict__ bmz,
    const float* __restrict__ Wgz, const float* __restrict__ bgz, float* __restrict__ bgconst)
{
    __shared__ float bconst[64];
    const int tid = threadIdx.x;
    if (tid < 64) {
        float s = bmz[tid];
        for (int kp = 0; kp < 3; ++kp)
            for (int f = 0; f < 64; ++f) s += bvz[f] * Wmz[kp * 4096 + f * 64 + tid];
        bconst[tid] = s;
    }
    __syncthreads();
    int g = tid >> 6, fo = tid & 63;
    float s = bgz[g * 64 + fo];
    for (int e = 0; e < 64; ++e) s += bconst[e] * Wgz[g * 4096 + e * 64 + fo];
    bgconst[tid] = s;
}

// ====== VcatT build for layer 0: VcatT[(l*16+b)*64+e][kp*1024+n], bf16 ======
__global__ __launch_bounds__(256) void vcat0T_kernel(
    const float* __restrict__ hist, const float* __restrict__ Wvc0,
    bf16* __restrict__ VcatT, int l0, int LC)
{
    __shared__ float xs[3][1024];
    __shared__ float Ws[576];
    const int lb = blockIdx.x;   // l*16+b
    const int l = lb >> 4, b = lb & 15;
    const int eq = blockIdx.y;   // e quarter
    const int tid = threadIdx.x;
    for (int i = tid; i < 576; i += 256) Ws[i] = Wvc0[i];
    const float* xp = hist + ((size_t)b * L_ + (l0 + l)) * N_ * 3;
    for (int i = tid; i < 3072; i += 256) xs[i % 3][i / 3] = xp[i];
    __syncthreads();
    bf16* outb = VcatT + (size_t)lb * 64 * 3072;
#pragma unroll
    for (int kp = 0; kp < 3; ++kp)
        for (int ei = 0; ei < 16; ++ei) {
            int e = eq * 16 + ei;
            float w0 = Ws[kp * 192 + e], w1 = Ws[kp * 192 + 64 + e], w2 = Ws[kp * 192 + 128 + e];
            bf16* rp = outb + (size_t)e * 3072 + kp * 1024;
#pragma unroll
            for (int q = 0; q < 4; ++q) {
                int n = q * 256 + tid;
                rp[n] = __float2bfloat16(fmaf(xs[0][n], w0, fmaf(xs[1][n], w1, xs[2][n] * w2)));
            }
        }
}

// ================= bf16 MFMA GEMM (NT): C = A @ BT^T =================
// T2 swizzle: LDS dest linear (global_load_lds), global source col pre-swizzled
// by ((lane&7)^(lane>>3))*8; reads use ko ^ ((row&7)<<3). Involution both sides.
__device__ __forceinline__ void gload16(const bf16* g, bf16* l)
{
    __builtin_amdgcn_global_load_lds((const __attribute__((address_space(1))) void*)g,
                                     (__attribute__((address_space(3))) void*)l, 16, 0, 0);
}

// REMAP=1: per-(l,b) slice V-build. BT += blockIdx.z*64 (row stride ldb=LC*1024);
// output row gr=(kp*64+e) scattered to Cp + blockIdx.z*64*3072 + e*3072 + kp*1024 + gc;
// rows gr >= Nmask skipped (zero-pad region).
template <int OUT_BF16, int REMAP>
__global__ __launch_bounds__(256) void gemm_mfma(
    const bf16* __restrict__ A, const bf16* __restrict__ BT, void* __restrict__ Cp,
    int M, int N, int K, int lda, int ldb, int ldc,
    const float* __restrict__ bias, int Nmask)
{
    __shared__ __align__(16) bf16 As[128 * 64];
    __shared__ __align__(16) bf16 Bs[128 * 64];
    const int tid = threadIdx.x;
    const int lane = tid & 63, w = tid >> 6;
    const int wr = w >> 1, wc = w & 1;
    const int row0 = blockIdx.y * 128, col0 = blockIdx.x * 128;
    if (REMAP) BT += (size_t)blockIdx.z * 64;

    f32x4 acc[4][4];
#pragma unroll
    for (int i = 0; i < 4; ++i)
#pragma unroll
        for (int j = 0; j < 4; ++j) acc[i][j] = (f32x4){0.f, 0.f, 0.f, 0.f};

    const int srow = w * 32 + (lane >> 3);
    const int scolsw = ((lane & 7) ^ (lane >> 3)) * 8;   // pre-swizzled k offset

    for (int k0 = 0; k0 < K; k0 += 64) {
#pragma unroll
        for (int i = 0; i < 4; ++i) {
            gload16(A + (size_t)(row0 + srow + i * 8) * lda + k0 + scolsw,
                    &As[(w * 32 + i * 8) * 64]);
            gload16(BT + (size_t)(col0 + srow + i * 8) * ldb + k0 + scolsw,
                    &Bs[(w * 32 + i * 8) * 64]);
        }
        __syncthreads();
#pragma unroll
        for (int kk = 0; kk < 64; kk += 32) {
            s16x8 af[4], bfr[4];
            const int ko = (kk + (lane >> 4) * 8) ^ ((lane & 7) << 3);
#pragma unroll
            for (int mi = 0; mi < 4; ++mi)
                af[mi] = *(const s16x8*)&As[(wr * 64 + mi * 16 + (lane & 15)) * 64 + ko];
#pragma unroll
            for (int ni = 0; ni < 4; ++ni)
                bfr[ni] = *(const s16x8*)&Bs[(wc * 64 + ni * 16 + (lane & 15)) * 64 + ko];
#pragma unroll
            for (int mi = 0; mi < 4; ++mi)
#pragma unroll
                for (int ni = 0; ni < 4; ++ni)
                    acc[mi][ni] = __builtin_amdgcn_mfma_f32_16x16x32_bf16(
                        af[mi], bfr[ni], acc[mi][ni], 0, 0, 0);
        }
        __syncthreads();
    }

    if (REMAP) {
        bf16* outb = (bf16*)Cp + (size_t)blockIdx.z * (64 * 3072);
#pragma unroll
        for (int mi = 0; mi < 4; ++mi) {
            const int gr = row0 + wr * 64 + mi * 16 + (lane >> 4) * 4;
#pragma unroll
            for (int ni = 0; ni < 4; ++ni) {
                const int gc = col0 + wc * 64 + ni * 16 + (lane & 15);
#pragma unroll
                for (int j = 0; j < 4; ++j) {
                    const int r = gr + j;
                    if (r >= Nmask) continue;
                    outb[(size_t)(r & 63) * 3072 + (r >> 6) * 1024 + gc] =
                        __float2bfloat16(acc[mi][ni][j]);
                }
            }
        }
        return;
    }

#pragma unroll
    for (int mi = 0; mi < 4; ++mi) {
        const int gr = row0 + wr * 64 + mi * 16 + (lane >> 4) * 4;
#pragma unroll
        for (int ni = 0; ni < 4; ++ni) {
            const int gc = col0 + wc * 64 + ni * 16 + (lane & 15);
            if (gc >= Nmask) continue;
            const float bb = bias ? bias[gc] : 0.f;
#pragma unroll
            for (int j = 0; j < 4; ++j) {
                float v = acc[mi][ni][j] + bb;
                if (OUT_BF16)
                    ((bf16*)Cp)[(size_t)(gr + j) * ldc + gc] = __float2bfloat16(v);
                else
                    ((float*)Cp)[(size_t)(gr + j) * ldc + gc] = v;
            }
        }
    }
}

// ========== fused gates GEMM (16x256,K=64 MFMA per step) + LSTM scan ==========
__global__ __launch_bounds__(256) void fused_gates_scan(
    const bf16* __restrict__ HG, const bf16* __restrict__ WgcT,
    const float* __restrict__ bgc, float* __restrict__ ct_buf,
    bf16* __restrict__ ht_out, float* __restrict__ htlast,
    int LC, int l0, int initct)
{
    __shared__ __align__(16) bf16 As[192 * 64];
    __shared__ __align__(16) bf16 Bs[256 * 64];
    __shared__ float gbuf[16 * 260];   // padded rows: 260 floats
    __shared__ float bgs[256];
    const int tid = threadIdx.x;
    const int lane = tid & 63, w = tid >> 6;
    const int n = blockIdx.x;
    const int swz = ((lane & 7) ^ (lane >> 3)) * 8;
    const int l8 = (lane >> 3) * 64;

#pragma unroll
    for (int r = 0; r < 8; ++r)
        gload16(WgcT + r * 2048 + w * 512 + l8 + swz, &Bs[r * 2048 + w * 512]);
    const bf16* HGn = HG + (size_t)n * LC * 1024;
    const int totA = LC * 1024;
    for (int r = 0; r * 2048 < totA; ++r) {
        int seg = r * 2048 + w * 512;
        if (seg < totA) gload16(HGn + seg + l8 + swz, &As[seg]);
    }
    bgs[tid] = bgc[tid];
    __syncthreads();

    float ct[4];
    const size_t cbase = (size_t)n * 1024;
#pragma unroll
    for (int it = 0; it < 4; ++it)
        ct[it] = initct ? 0.f : ct_buf[cbase + it * 256 + tid];

    const int ar = (lane & 15);
    const int ak = (lane >> 4) * 8;
    const int kswz = (lane & 7) << 3;
    for (int l = 0; l < LC; ++l) {
        f32x4 acc[4];
#pragma unroll
        for (int ni = 0; ni < 4; ++ni) acc[ni] = (f32x4){0.f, 0.f, 0.f, 0.f};
#pragma unroll
        for (int kk = 0; kk < 64; kk += 32) {
            const int ko = (ak + kk) ^ kswz;
            s16x8 af = *(const s16x8*)&As[(l * 16 + ar) * 64 + ko];
#pragma unroll
            for (int ni = 0; ni < 4; ++ni) {
                s16x8 bf = *(const s16x8*)&Bs[(w * 64 + ni * 16 + ar) * 64 + ko];
                acc[ni] = __builtin_amdgcn_mfma_f32_16x16x32_bf16(af, bf, acc[ni], 0, 0, 0);
            }
        }
        __syncthreads();   // previous scan's gbuf reads complete
#pragma unroll
        for (int ni = 0; ni < 4; ++ni)
#pragma unroll
            for (int j = 0; j < 4; ++j)
                gbuf[((lane >> 4) * 4 + j) * 260 + w * 64 + ni * 16 + (lane & 15)] = acc[ni][j];
        __syncthreads();
        const size_t hbase = ((size_t)n * LC + l) * 1024;
        const bool last = (l0 + l == L_ - 1);
#pragma unroll
        for (int it = 0; it < 4; ++it) {
            const int flat = it * 256 + tid;
            const int bi = (flat >> 6) * 260 + (flat & 63);
            const int f = flat & 63;
            float xf = gbuf[bi] + bgs[f];
            float xi = gbuf[bi + 64] + bgs[64 + f];
            float xg = gbuf[bi + 128] + bgs[128 + f];
            float xo = gbuf[bi + 192] + bgs[192 + f];
            float fg = 1.f / (1.f + __expf(-xf));
            float ig = 1.f / (1.f + __expf(-xi));
            float gg = 2.f / (1.f + __expf(-2.f * xg)) - 1.f;
            float og = 1.f / (1.f + __expf(-xo));
            ct[it] = fg * ct[it] + ig * gg;
            float ht = og * (2.f / (1.f + __expf(-2.f * ct[it])) - 1.f);
            if (ht_out) ht_out[hbase + flat] = __float2bfloat16(ht);
            if (htlast && last) htlast[cbase + flat] = ht;
        }
    }
#pragma unroll
    for (int it = 0; it < 4; ++it)
        ct_buf[cbase + it * 256 + tid] = ct[it];
}

// ================= decoder =================
__global__ __launch_bounds__(256) void decoder_kernel(
    const float* __restrict__ h0, const float* __restrict__ h1,
    const float* __restrict__ Wdec, const float* __restrict__ bdec,
    const float* __restrict__ Wout, const float* __restrict__ bout,
    float* __restrict__ outp)
{
    __shared__ float Wd[12 * 2 * 64];
    __shared__ float Wo[144];
    __shared__ float bd[12], bo[12];
    const int tid = threadIdx.x;
    for (int i = tid; i < 12 * 2 * 64; i += 256) Wd[i] = Wdec[i];
    for (int i = tid; i < 144; i += 256) Wo[i] = Wout[i];
    if (tid < 12) { bd[tid] = bdec[tid]; bo[tid] = bout[tid]; }
    __syncthreads();
    const int gid = blockIdx.x * 256 + tid;   // b*1024 + n
    const int b = gid >> 10, n = gid & 1023;
    const float* h0r = h0 + ((size_t)n * 16 + b) * 64;
    const float* h1r = h1 + ((size_t)n * 16 + b) * 64;
    float dec[12];
#pragma unroll
    for (int o = 0; o < 12; ++o) dec[o] = bd[o];
    for (int e = 0; e < 64; ++e) {
        float v0 = h0r[e], v1 = h1r[e];
#pragma unroll
        for (int o = 0; o < 12; ++o) dec[o] += v0 * Wd[o * 128 + e] + v1 * Wd[o * 128 + 64 + e];
    }
#pragma unroll
    for (int o = 0; o < 12; ++o) {
        float s = bo[o];
#pragma unroll
        for (int p = 0; p < 12; ++p) s += Wo[o * 12 + p] * dec[p];
        outp[((size_t)b * 12 + o) * 1024 + n] = s;
    }
}

extern "C" void kernel_launch(void* const* d_in, const int* in_sizes, int n_in,
                              void* d_out, int out_size, void* d_ws, size_t ws_size,
                              hipStream_t stream)
{
    const float* hist = (const float*)d_in[0];
    const float* adj  = (const float*)d_in[1];
    const float* Wv0  = (const float*)d_in[2];
    const float* Wv1  = (const float*)d_in[3];
    const float* bv   = (const float*)d_in[4];
    const float* E    = (const float*)d_in[5];
    const float* Wq   = (const float*)d_in[6];
    const float* Wk   = (const float*)d_in[7];
    const float* Eg1  = (const float*)d_in[8];
    const float* Eg2  = (const float*)d_in[9];
    const float* Wmix = (const float*)d_in[10];
    const float* bmix = (const float*)d_in[11];
    const float* Wg   = (const float*)d_in[12];
    const float* bg   = (const float*)d_in[13];
    const float* Wdec = (const float*)d_in[14];
    const float* bdec = (const float*)d_in[15];
    const float* Wout = (const float*)d_in[16];
    const float* bout = (const float*)d_in[17];
    float* outp = (float*)d_out;
    (void)in_sizes; (void)n_in; (void)out_size;

    char* ws = (char*)d_ws;
    size_t off = 0;
    auto alloc = [&](size_t bytes) -> void* {
        void* p = (void*)(ws + off);
        off += (bytes + 255) & ~(size_t)255;
        return p;
    };
    bf16*  Mcatb0 = (bf16*)alloc((size_t)1024 * 3072 * 2);   // [M1|M2|attn] bf16
    bf16*  Mcatb1 = (bf16*)alloc((size_t)1024 * 3072 * 2);
    float* attnf  = (float*)alloc((size_t)1024 * 1024 * 4);
    bf16*  attnT  = (bf16*)alloc((size_t)1024 * 1024 * 2);
    bf16*  adjb   = (bf16*)alloc((size_t)1024 * 1024 * 2);
    bf16*  adpb   = (bf16*)alloc((size_t)1024 * 1024 * 2);
    float* qb     = (float*)alloc((size_t)1024 * 64 * 4);
    float* kb     = (float*)alloc((size_t)1024 * 64 * 4);
    float* logits = (float*)alloc((size_t)1024 * 1024 * 4);
    float* Wvc0   = (float*)alloc(3 * 3 * 64 * 4);           // [kp][c][e]
    float* Wvc1   = (float*)alloc(3 * 64 * 64 * 4);          // [kp][f][e]
    bf16*  Wvc1T  = (bf16*)alloc(256 * 64 * 2);
    bf16*  WgcT0  = (bf16*)alloc(256 * 64 * 2);
    bf16*  WgcT1  = (bf16*)alloc(256 * 64 * 2);
    float* bgc0   = (float*)alloc(256 * 4);
    float* bgc1   = (float*)alloc(256 * 4);
    float* ct0    = (float*)alloc((size_t)N_ * B_ * 64 * 4);
    float* ct1    = (float*)alloc((size_t)N_ * B_ * 64 * 4);
    float* hl0    = (float*)alloc((size_t)N_ * B_ * 64 * 4);
    float* hl1    = (float*)alloc((size_t)N_ * B_ * 64 * 4);
    size_t fixed = off;

    // per-LC-unit scratch: VcatT 6MiB + HG 2MiB + ht0c 2MiB = 10MiB
    static const int divs[] = {12, 8, 6, 4, 2, 1};
    int LC = 1;
    for (int di = 0; di < 6; ++di) {
        if (fixed + (size_t)divs[di] * 10485760ull + 65536 <= ws_size) { LC = divs[di]; break; }
    }
    bf16*  VcatT = (bf16*)alloc((size_t)LC * 6291456ull);   // (LC*1024) x 3072
    bf16*  HG    = (bf16*)alloc((size_t)LC * 2097152ull);   // 1024 x (LC*1024)
    bf16*  ht0c  = (bf16*)alloc((size_t)LC * 2097152ull);   // Mrows x 64

    dim3 blk(256);
    bf16*  McatB[2] = {Mcatb0, Mcatb1};
    bf16*  WgcT[2] = {WgcT0, WgcT1};
    float* bgc[2] = {bgc0, bgc1};

    f2b_kernel<<<4096, blk, 0, stream>>>(adj, adjb, 1024 * 1024);
    for (int z = 0; z < 2; ++z) {
        const float* Ez = E + (size_t)z * N_ * 64;
        gemm_nn<<<dim3(1, 16), blk, 0, stream>>>(Ez, Wq + z * 4096, qb, 1024, 64, 64, 64, 64, 64, nullptr);
        gemm_nn<<<dim3(1, 16), blk, 0, stream>>>(Ez, Wk + z * 4096, kb, 1024, 64, 64, 64, 64, 64, nullptr);
        gemm_nt<<<dim3(16, 16), blk, 0, stream>>>(qb, kb, logits, 1024, 64, 0.125f);
        row_softmax<<<1024, blk, 0, stream>>>(logits, attnf, 1024, McatB[z] + 2048, 3072, 0);
        transpose_f2b<<<dim3(16, 16), blk, 0, stream>>>(attnf, attnT);
        gemm_nt<<<dim3(16, 16), blk, 0, stream>>>(Eg1 + z * 16384, Eg2 + z * 16384, logits, 1024, 16, 1.f);
        row_softmax<<<1024, blk, 0, stream>>>(logits, nullptr, 0, adpb, 1024, 1);
        gemm_mfma<1, 0><<<dim3(8, 8), blk, 0, stream>>>(adjb, attnT, McatB[z],
            1024, 1024, 1024, 1024, 1024, 3072, nullptr, 1024);
        gemm_mfma<1, 0><<<dim3(8, 8), blk, 0, stream>>>(adpb, attnT, McatB[z] + 1024,
            1024, 1024, 1024, 1024, 1024, 3072, nullptr, 1024);
        if (z == 0) {
            for (int kp = 0; kp < 3; ++kp)
                gemm_nn<<<dim3(1, 1), blk, 0, stream>>>(Wv0, Wmix + kp * 4096,
                    Wvc0 + kp * 3 * 64, 3, 64, 64, 64, 64, 64, nullptr);
        } else {
            for (int kp = 0; kp < 3; ++kp)
                gemm_nn<<<dim3(1, 1), blk, 0, stream>>>(Wv1, Wmix + 12288 + kp * 4096,
                    Wvc1 + kp * 4096, 64, 64, 64, 64, 64, 64, nullptr);
            wvc1t_kernel<<<64, blk, 0, stream>>>(Wvc1, Wvc1T);
        }
        wgct_kernel<<<64, blk, 0, stream>>>(Wg + z * 16384, WgcT[z]);
        bias_kernel<<<1, blk, 0, stream>>>(bv + z * 64, Wmix + z * 12288, bmix + z * 64,
            Wg + z * 16384, bg + z * 256, bgc[z]);
    }

    const int nch = L_ / LC;
    for (int c = 0; c < nch; ++c) {
        const int l0 = c * LC;
        // ---- layer 0 ----
        vcat0T_kernel<<<dim3(LC * 16, 4), blk, 0, stream>>>(hist, Wvc0, VcatT, l0, LC);
        gemm_mfma<1, 0><<<dim3(LC * 8, 8), blk, 0, stream>>>(Mcatb0, VcatT, HG,
            1024, LC * 1024, 3072, 3072, 3072, LC * 1024, nullptr, LC * 1024);
        fused_gates_scan<<<1024, blk, 0, stream>>>(HG, WgcT0, bgc0, ct0,
            ht0c, hl0, LC, l0, c == 0);
        // ---- layer 1: V build straight into VcatT (REMAP epilogue) ----
        gemm_mfma<1, 1><<<dim3(8, 2, LC * 16), blk, 0, stream>>>(Wvc1T, ht0c, VcatT,
            256, 1024, 64, 64, LC * 1024, 0, nullptr, 192);
        gemm_mfma<1, 0><<<dim3(LC * 8, 8), blk, 0, stream>>>(Mcatb1, VcatT, HG,
            1024, LC * 1024, 3072, 3072, 3072, LC * 1024, nullptr, LC * 1024);
        fused_gates_scan<<<1024, blk, 0, stream>>>(HG, WgcT1, bgc1, ct1,
            nullptr, hl1, LC, l0, c == 0);
    }
    decoder_kernel<<<64, blk, 0, stream>>>(hl0, hl1, Wdec, bdec, Wout, bout, outp);
}